// Round 1
// baseline (3171.888 us; speedup 1.0000x reference)
//
#include <hip/hip_runtime.h>
#include <cstdint>
#include <cstddef>

#define BB 8
#define HH 8
#define NN 1024
#define CC 256
#define OUTCH 4096   // 2*H*C

// ---------------------------------------------------------------------------
// Generic f32 GEMM: C = alpha * A @ B^T
// A: [M,K] lda ; B: [N,K] ldb ; C: [M,N] ldc.
// Batch via blockIdx.z decomposed as (b,h) with per-axis element strides.
// All of M,N multiples of 64; K multiple of 16.
// ---------------------------------------------------------------------------
__global__ __launch_bounds__(256) void gemm_abt_kernel(
    const float* __restrict__ A, const float* __restrict__ Bm, float* __restrict__ Cm,
    int K, int lda, int ldb, int ldc, int Hdim,
    long long sAb, long long sAh, long long sBb, long long sBh,
    long long sCb, long long sCh, float alpha)
{
  const int z = blockIdx.z;
  const int b = z / Hdim, h = z - b * Hdim;
  A  += (size_t)b * sAb + (size_t)h * sAh;
  Bm += (size_t)b * sBb + (size_t)h * sBh;
  Cm += (size_t)b * sCb + (size_t)h * sCh;

  __shared__ float As[16][64];
  __shared__ float Bs[16][64];

  const int tid = threadIdx.x;
  const int bi = blockIdx.y * 64;
  const int bj = blockIdx.x * 64;
  const int tr = tid >> 4;          // 0..15
  const int tc = tid & 15;          // 0..15
  const int lrow = tid >> 2;        // 0..63
  const int lk = (tid & 3) << 2;    // 0,4,8,12

  const float* ap = A  + (size_t)(bi + lrow) * lda + lk;
  const float* bp = Bm + (size_t)(bj + lrow) * ldb + lk;

  float acc[4][4] = {};

  for (int k0 = 0; k0 < K; k0 += 16) {
    const float4 av = *(const float4*)(ap + k0);
    const float4 bv = *(const float4*)(bp + k0);
    __syncthreads();
    As[lk+0][lrow]=av.x; As[lk+1][lrow]=av.y; As[lk+2][lrow]=av.z; As[lk+3][lrow]=av.w;
    Bs[lk+0][lrow]=bv.x; Bs[lk+1][lrow]=bv.y; Bs[lk+2][lrow]=bv.z; Bs[lk+3][lrow]=bv.w;
    __syncthreads();
#pragma unroll
    for (int kk = 0; kk < 16; ++kk) {
      const float4 a = *(const float4*)(&As[kk][tr<<2]);
      const float4 v = *(const float4*)(&Bs[kk][tc<<2]);
      acc[0][0] += a.x*v.x; acc[0][1] += a.x*v.y; acc[0][2] += a.x*v.z; acc[0][3] += a.x*v.w;
      acc[1][0] += a.y*v.x; acc[1][1] += a.y*v.y; acc[1][2] += a.y*v.z; acc[1][3] += a.y*v.w;
      acc[2][0] += a.z*v.x; acc[2][1] += a.z*v.y; acc[2][2] += a.z*v.z; acc[2][3] += a.z*v.w;
      acc[3][0] += a.w*v.x; acc[3][1] += a.w*v.y; acc[3][2] += a.w*v.z; acc[3][3] += a.w*v.w;
    }
  }
#pragma unroll
  for (int i = 0; i < 4; ++i) {
    float4 o;
    o.x = acc[i][0]*alpha; o.y = acc[i][1]*alpha;
    o.z = acc[i][2]*alpha; o.w = acc[i][3]*alpha;
    *(float4*)(Cm + (size_t)(bi + (tr<<2) + i) * ldc + bj + (tc<<2)) = o;
  }
}

// ---------------------------------------------------------------------------
// In-place row softmax over last dim (N=1024), one block per row.
// ---------------------------------------------------------------------------
__global__ __launch_bounds__(256) void softmax_kernel(float* __restrict__ attn)
{
  const size_t row = blockIdx.x;
  float* ar = attn + row * NN;
  const int t = threadIdx.x;
  __shared__ float red[256];

  float4 x = *(float4*)(ar + (t << 2));
  float mx = fmaxf(fmaxf(x.x, x.y), fmaxf(x.z, x.w));
  red[t] = mx; __syncthreads();
  for (int s = 128; s > 0; s >>= 1) { if (t < s) red[t] = fmaxf(red[t], red[t+s]); __syncthreads(); }
  const float M = red[0]; __syncthreads();

  float e0 = expf(x.x - M), e1 = expf(x.y - M), e2 = expf(x.z - M), e3 = expf(x.w - M);
  red[t] = e0 + e1 + e2 + e3; __syncthreads();
  for (int s = 128; s > 0; s >>= 1) { if (t < s) red[t] += red[t+s]; __syncthreads(); }
  const float inv = 1.0f / red[0];

  float4 o; o.x = e0*inv; o.y = e1*inv; o.z = e2*inv; o.w = e3*inv;
  *(float4*)(ar + (t << 2)) = o;
}

// ---------------------------------------------------------------------------
// sum_edge[b,n,m] = sum_h attn[b,h,n,m].  One block per (b,n).
// ---------------------------------------------------------------------------
__global__ __launch_bounds__(256) void sum_edge_kernel(const float* __restrict__ attn,
                                                       float* __restrict__ se)
{
  const int bn = blockIdx.x;
  const int b = bn >> 10;
  const int n = bn & 1023;
  const int t = threadIdx.x;
  const float* base = attn + ((size_t)b * HH * NN + n) * NN;   // attn[b,0,n,:]
  float4 s = make_float4(0.f, 0.f, 0.f, 0.f);
#pragma unroll
  for (int h = 0; h < HH; ++h) {
    const float4 v = *(const float4*)(base + (size_t)h * NN * NN + (t << 2));
    s.x += v.x; s.y += v.y; s.z += v.z; s.w += v.w;
  }
  *(float4*)(se + (size_t)bn * NN + (t << 2)) = s;
}

// ---------------------------------------------------------------------------
// Top-5 per row of sum_edge; set colmask[b, idx] = 1 for each winner.
// Tie-break: lowest index first (matches jax.lax.top_k). Values are > 0.
// ---------------------------------------------------------------------------
__global__ __launch_bounds__(256) void topk_kernel(const float* __restrict__ se,
                                                   float* __restrict__ colmask)
{
  const int bn = blockIdx.x;
  const int b = bn >> 10;
  const int t = threadIdx.x;
  __shared__ float vals[NN];
  __shared__ unsigned long long red[256];
  const float* rowp = se + (size_t)bn * NN;
  for (int i = t; i < NN; i += 256) vals[i] = rowp[i];
  __syncthreads();

  for (int it = 0; it < 5; ++it) {
    unsigned long long best = 0ull;
    for (int i = t; i < NN; i += 256) {
      const float v = vals[i];
      if (v >= 0.f) {
        // positive floats: bit pattern is order-preserving
        unsigned long long key =
            ((unsigned long long)__float_as_uint(v) << 32) | (unsigned)(NN - 1 - i);
        if (key > best) best = key;
      }
    }
    red[t] = best; __syncthreads();
    for (int s = 128; s > 0; s >>= 1) {
      if (t < s) red[t] = red[t] > red[t+s] ? red[t] : red[t+s];
      __syncthreads();
    }
    if (t == 0) {
      const int idx = NN - 1 - (int)(red[0] & 0xFFFFFFFFull);
      colmask[b * NN + idx] = 1.0f;
      vals[idx] = -1.0f;
    }
    __syncthreads();
  }
}

// ---------------------------------------------------------------------------
// inv_rs[b,h,n] = 1 / (sum_m mask(n,m)*attn[b,h,n,m] + 1e-16). Block per row.
// ---------------------------------------------------------------------------
__global__ __launch_bounds__(256) void rs_kernel(const float* __restrict__ attn,
                                                 const float* __restrict__ colmask,
                                                 float* __restrict__ inv_rs)
{
  const int row = blockIdx.x;         // (b*H+h)*N + n
  const int n = row & 1023;
  const int bh = row >> 10;
  const int b = bh >> 3;
  const int t = threadIdx.x;
  const float* ar = attn + (size_t)row * NN;
  const float* cm = colmask + b * NN;
  const int m = t << 2;
  const float4 v = *(const float4*)(ar + m);
  const float4 c = *(const float4*)(cm + m);
  float acc = 0.f;
  acc += ((c.x != 0.f) || (m + 0 == n)) ? v.x : 0.f;
  acc += ((c.y != 0.f) || (m + 1 == n)) ? v.y : 0.f;
  acc += ((c.z != 0.f) || (m + 2 == n)) ? v.z : 0.f;
  acc += ((c.w != 0.f) || (m + 3 == n)) ? v.w : 0.f;
  __shared__ float red[256];
  red[t] = acc; __syncthreads();
  for (int s = 128; s > 0; s >>= 1) { if (t < s) red[t] += red[t+s]; __syncthreads(); }
  if (t == 0) inv_rs[row] = 1.0f / (red[0] + 1e-16f);
}

// ---------------------------------------------------------------------------
// isc[b,h,m] = 1/sqrt( sum_n mask(n,m)*attn[b,h,n,m]*inv_rs[b,h,n] + 1e-16 ).
// Grid: (N/256, B*H); thread owns one column m, loops n. Deterministic.
// ---------------------------------------------------------------------------
__global__ __launch_bounds__(256) void cs_kernel(const float* __restrict__ attn,
                                                 const float* __restrict__ colmask,
                                                 const float* __restrict__ inv_rs,
                                                 float* __restrict__ isc)
{
  const int bh = blockIdx.y;
  const int b = bh >> 3;
  const int m = blockIdx.x * 256 + threadIdx.x;
  const float* ab = attn + (size_t)bh * NN * NN;
  const float* ir = inv_rs + bh * NN;
  const float cmv = colmask[b * NN + m];
  float acc = 0.f;
  for (int n = 0; n < NN; ++n) {
    const float v = ab[(size_t)n * NN + m];
    const float e = (cmv != 0.f || m == n) ? v : 0.f;
    acc += e * ir[n];
  }
  isc[bh * NN + m] = 1.0f / sqrtf(acc + 1e-16f);
}

// ---------------------------------------------------------------------------
// G[b,h,n,m] = mask(n,m)*attn[b,h,n,m] * inv_rs[b,h,n] * isc[b,h,m]
// ---------------------------------------------------------------------------
__global__ __launch_bounds__(256) void g_kernel(const float* __restrict__ attn,
                                                const float* __restrict__ colmask,
                                                const float* __restrict__ inv_rs,
                                                const float* __restrict__ isc,
                                                float* __restrict__ G)
{
  const size_t idx = ((size_t)blockIdx.x * 256 + threadIdx.x) << 2;
  const size_t row = idx >> 10;      // (b*H+h)*N + n
  const int m = (int)(idx & 1023);
  const int n = (int)(row & 1023);
  const int bh = (int)(row >> 10);
  const int b = bh >> 3;
  const float4 v = *(const float4*)(attn + idx);
  const float4 c = *(const float4*)(colmask + b * NN + m);
  const float4 s = *(const float4*)(isc + bh * NN + m);
  const float ir = inv_rs[row];
  float4 o;
  o.x = (((c.x != 0.f) || (m + 0 == n)) ? v.x : 0.f) * ir * s.x;
  o.y = (((c.y != 0.f) || (m + 1 == n)) ? v.y : 0.f) * ir * s.y;
  o.z = (((c.z != 0.f) || (m + 2 == n)) ? v.z : 0.f) * ir * s.z;
  o.w = (((c.w != 0.f) || (m + 3 == n)) ? v.w : 0.f) * ir * s.w;
  *(float4*)(G + idx) = o;
}

// ---------------------------------------------------------------------------
extern "C" void kernel_launch(void* const* d_in, const int* in_sizes, int n_in,
                              void* d_out, int out_size, void* d_ws, size_t ws_size,
                              hipStream_t stream)
{
  const float* x = (const float*)d_in[0];   // [B,N,C]
  const float* W = (const float*)d_in[1];   // [2*H*C, C]
  float* attn = (float*)d_out;              // used as attn scratch, then final out
  char* ws = (char*)d_ws;

  // workspace layout (bytes)
  const size_t G_BYTES = (size_t)BB * HH * NN * NN * 4;     // 268435456
  float* qk    = (float*)(ws + 0);                          // [B*N, 4096] (dead before G)
  float* G     = (float*)(ws + 0);                          // [B,H,N,N]
  float* se    = (float*)(ws + G_BYTES);                    // [B,N,N]
  float* cmask = (float*)(ws + G_BYTES + (size_t)BB*NN*NN*4);
  float* irs   = (float*)(ws + G_BYTES + (size_t)BB*NN*NN*4 + (size_t)BB*NN*4);
  float* isc   = (float*)(ws + G_BYTES + (size_t)BB*NN*NN*4 + (size_t)BB*NN*4
                              + (size_t)BB*HH*NN*4);

  const long long NNll = NN, HNN = (long long)HH * NN * NN, NN2 = (long long)NN * NN;

  // 1. qk = x @ W^T : [8192, 4096]
  hipLaunchKernelGGL(gemm_abt_kernel, dim3(OUTCH/64, (BB*NN)/64, 1), dim3(256), 0, stream,
                     x, W, qk, CC, CC, CC, OUTCH, 1,
                     0LL, 0LL, 0LL, 0LL, 0LL, 0LL, 1.0f);

  // 2. logits[b,h] = scale * q_bh @ k_bh^T  -> attn buffer (d_out)
  //    q row (b,h,n): qk + b*N*4096 + n*4096 + h*256 ; k adds +2048.
  hipLaunchKernelGGL(gemm_abt_kernel, dim3(NN/64, NN/64, BB*HH), dim3(256), 0, stream,
                     qk, qk + 2048, attn, CC, OUTCH, OUTCH, NN, HH,
                     (long long)NN * OUTCH, 256LL,
                     (long long)NN * OUTCH, 256LL,
                     HNN, NN2, 0.0625f /* 1/sqrt(256) */);

  // 3. softmax rows in place
  hipLaunchKernelGGL(softmax_kernel, dim3(BB*HH*NN), dim3(256), 0, stream, attn);

  // 4. sum over heads
  hipLaunchKernelGGL(sum_edge_kernel, dim3(BB*NN), dim3(256), 0, stream, attn, se);

  // 5. top-5 union -> column mask
  hipMemsetAsync(cmask, 0, (size_t)BB * NN * 4, stream);
  hipLaunchKernelGGL(topk_kernel, dim3(BB*NN), dim3(256), 0, stream, se, cmask);

  // 6. row sums (reciprocal)
  hipLaunchKernelGGL(rs_kernel, dim3(BB*HH*NN), dim3(256), 0, stream, attn, cmask, irs);

  // 7. column sums (inverse sqrt)
  hipLaunchKernelGGL(cs_kernel, dim3(NN/256, BB*HH), dim3(256), 0, stream,
                     attn, cmask, irs, isc);

  // 8. G = e * inv_rs * isc
  hipLaunchKernelGGL(g_kernel, dim3((BB*HH*NN*(long long)NN) / 4 / 256), dim3(256), 0, stream,
                     attn, cmask, irs, isc, G);

  // 9. out[b,h] = G_bh @ G_bh^T  (overwrites attn in d_out)
  hipLaunchKernelGGL(gemm_abt_kernel, dim3(NN/64, NN/64, BB*HH), dim3(256), 0, stream,
                     G, G, attn, NN, NN, NN, NN, HH,
                     HNN, NN2, HNN, NN2, HNN, NN2, 1.0f);

  (void)in_sizes; (void)n_in; (void)out_size; (void)ws_size;
}

// Round 2
// 1415.054 us; speedup vs baseline: 2.2415x; 2.2415x over previous
//
#include <hip/hip_runtime.h>
#include <hip/hip_bf16.h>
#include <cstdint>
#include <cstddef>

#define BB 8
#define HH 8
#define NN 1024
#define CC 256
#define OUTCH 4096   // 2*H*C

typedef __attribute__((ext_vector_type(8))) __bf16 bf16x8;
typedef __attribute__((ext_vector_type(4))) __bf16 bf16x4;
typedef __attribute__((ext_vector_type(4))) float f32x4;

// ---------------------------------------------------------------------------
// Generic f32 GEMM: C = alpha * A @ B^T   (used for x@W^T and q@k^T)
// ---------------------------------------------------------------------------
__global__ __launch_bounds__(256) void gemm_abt_kernel(
    const float* __restrict__ A, const float* __restrict__ Bm, float* __restrict__ Cm,
    int K, int lda, int ldb, int ldc, int Hdim,
    long long sAb, long long sAh, long long sBb, long long sBh,
    long long sCb, long long sCh, float alpha)
{
  const int z = blockIdx.z;
  const int b = z / Hdim, h = z - b * Hdim;
  A  += (size_t)b * sAb + (size_t)h * sAh;
  Bm += (size_t)b * sBb + (size_t)h * sBh;
  Cm += (size_t)b * sCb + (size_t)h * sCh;

  __shared__ float As[16][64];
  __shared__ float Bs[16][64];

  const int tid = threadIdx.x;
  const int bi = blockIdx.y * 64;
  const int bj = blockIdx.x * 64;
  const int tr = tid >> 4;
  const int tc = tid & 15;
  const int lrow = tid >> 2;
  const int lk = (tid & 3) << 2;

  const float* ap = A  + (size_t)(bi + lrow) * lda + lk;
  const float* bp = Bm + (size_t)(bj + lrow) * ldb + lk;

  float acc[4][4] = {};

  for (int k0 = 0; k0 < K; k0 += 16) {
    const float4 av = *(const float4*)(ap + k0);
    const float4 bv = *(const float4*)(bp + k0);
    __syncthreads();
    As[lk+0][lrow]=av.x; As[lk+1][lrow]=av.y; As[lk+2][lrow]=av.z; As[lk+3][lrow]=av.w;
    Bs[lk+0][lrow]=bv.x; Bs[lk+1][lrow]=bv.y; Bs[lk+2][lrow]=bv.z; Bs[lk+3][lrow]=bv.w;
    __syncthreads();
#pragma unroll
    for (int kk = 0; kk < 16; ++kk) {
      const float4 a = *(const float4*)(&As[kk][tr<<2]);
      const float4 v = *(const float4*)(&Bs[kk][tc<<2]);
      acc[0][0] += a.x*v.x; acc[0][1] += a.x*v.y; acc[0][2] += a.x*v.z; acc[0][3] += a.x*v.w;
      acc[1][0] += a.y*v.x; acc[1][1] += a.y*v.y; acc[1][2] += a.y*v.z; acc[1][3] += a.y*v.w;
      acc[2][0] += a.z*v.x; acc[2][1] += a.z*v.y; acc[2][2] += a.z*v.z; acc[2][3] += a.z*v.w;
      acc[3][0] += a.w*v.x; acc[3][1] += a.w*v.y; acc[3][2] += a.w*v.z; acc[3][3] += a.w*v.w;
    }
  }
#pragma unroll
  for (int i = 0; i < 4; ++i) {
    float4 o;
    o.x = acc[i][0]*alpha; o.y = acc[i][1]*alpha;
    o.z = acc[i][2]*alpha; o.w = acc[i][3]*alpha;
    *(float4*)(Cm + (size_t)(bi + (tr<<2) + i) * ldc + bj + (tc<<2)) = o;
  }
}

// ---------------------------------------------------------------------------
// In-place row softmax over last dim (N=1024), one block per row.
// ---------------------------------------------------------------------------
__global__ __launch_bounds__(256) void softmax_kernel(float* __restrict__ attn)
{
  const size_t row = blockIdx.x;
  float* ar = attn + row * NN;
  const int t = threadIdx.x;
  __shared__ float red[256];

  float4 x = *(float4*)(ar + (t << 2));
  float mx = fmaxf(fmaxf(x.x, x.y), fmaxf(x.z, x.w));
  red[t] = mx; __syncthreads();
  for (int s = 128; s > 0; s >>= 1) { if (t < s) red[t] = fmaxf(red[t], red[t+s]); __syncthreads(); }
  const float M = red[0]; __syncthreads();

  float e0 = expf(x.x - M), e1 = expf(x.y - M), e2 = expf(x.z - M), e3 = expf(x.w - M);
  red[t] = e0 + e1 + e2 + e3; __syncthreads();
  for (int s = 128; s > 0; s >>= 1) { if (t < s) red[t] += red[t+s]; __syncthreads(); }
  const float inv = 1.0f / red[0];

  float4 o; o.x = e0*inv; o.y = e1*inv; o.z = e2*inv; o.w = e3*inv;
  *(float4*)(ar + (t << 2)) = o;
}

// ---------------------------------------------------------------------------
// sum_edge[b,n,m] = sum_h attn[b,h,n,m].  One block per (b,n).
// ---------------------------------------------------------------------------
__global__ __launch_bounds__(256) void sum_edge_kernel(const float* __restrict__ attn,
                                                       float* __restrict__ se)
{
  const int bn = blockIdx.x;
  const int b = bn >> 10;
  const int n = bn & 1023;
  const int t = threadIdx.x;
  const float* base = attn + ((size_t)b * HH * NN + n) * NN;
  float4 s = make_float4(0.f, 0.f, 0.f, 0.f);
#pragma unroll
  for (int h = 0; h < HH; ++h) {
    const float4 v = *(const float4*)(base + (size_t)h * NN * NN + (t << 2));
    s.x += v.x; s.y += v.y; s.z += v.z; s.w += v.w;
  }
  *(float4*)(se + (size_t)bn * NN + (t << 2)) = s;
}

// ---------------------------------------------------------------------------
// Top-5 per row of sum_edge; set colmask[b, idx] = 1 for each winner.
// ---------------------------------------------------------------------------
__global__ __launch_bounds__(256) void topk_kernel(const float* __restrict__ se,
                                                   float* __restrict__ colmask)
{
  const int bn = blockIdx.x;
  const int b = bn >> 10;
  const int t = threadIdx.x;
  __shared__ float vals[NN];
  __shared__ unsigned long long red[256];
  const float* rowp = se + (size_t)bn * NN;
  for (int i = t; i < NN; i += 256) vals[i] = rowp[i];
  __syncthreads();

  for (int it = 0; it < 5; ++it) {
    unsigned long long best = 0ull;
    for (int i = t; i < NN; i += 256) {
      const float v = vals[i];
      if (v >= 0.f) {
        unsigned long long key =
            ((unsigned long long)__float_as_uint(v) << 32) | (unsigned)(NN - 1 - i);
        if (key > best) best = key;
      }
    }
    red[t] = best; __syncthreads();
    for (int s = 128; s > 0; s >>= 1) {
      if (t < s) red[t] = red[t] > red[t+s] ? red[t] : red[t+s];
      __syncthreads();
    }
    if (t == 0) {
      const int idx = NN - 1 - (int)(red[0] & 0xFFFFFFFFull);
      colmask[b * NN + idx] = 1.0f;
      vals[idx] = -1.0f;
    }
    __syncthreads();
  }
}

// ---------------------------------------------------------------------------
// inv_rs[b,h,n] = 1 / (sum_m mask(n,m)*attn[b,h,n,m] + 1e-16). Block per row.
// ---------------------------------------------------------------------------
__global__ __launch_bounds__(256) void rs_kernel(const float* __restrict__ attn,
                                                 const float* __restrict__ colmask,
                                                 float* __restrict__ inv_rs)
{
  const int row = blockIdx.x;
  const int n = row & 1023;
  const int bh = row >> 10;
  const int b = bh >> 3;
  const int t = threadIdx.x;
  const float* ar = attn + (size_t)row * NN;
  const float* cm = colmask + b * NN;
  const int m = t << 2;
  const float4 v = *(const float4*)(ar + m);
  const float4 c = *(const float4*)(cm + m);
  float acc = 0.f;
  acc += ((c.x != 0.f) || (m + 0 == n)) ? v.x : 0.f;
  acc += ((c.y != 0.f) || (m + 1 == n)) ? v.y : 0.f;
  acc += ((c.z != 0.f) || (m + 2 == n)) ? v.z : 0.f;
  acc += ((c.w != 0.f) || (m + 3 == n)) ? v.w : 0.f;
  __shared__ float red[256];
  red[t] = acc; __syncthreads();
  for (int s = 128; s > 0; s >>= 1) { if (t < s) red[t] += red[t+s]; __syncthreads(); }
  if (t == 0) inv_rs[row] = 1.0f / (red[0] + 1e-16f);
}

// ---------------------------------------------------------------------------
// isc[b,h,m] = 1/sqrt( sum_n mask(n,m)*attn[b,h,n,m]*inv_rs[b,h,n] + 1e-16 ).
// ---------------------------------------------------------------------------
__global__ __launch_bounds__(256) void cs_kernel(const float* __restrict__ attn,
                                                 const float* __restrict__ colmask,
                                                 const float* __restrict__ inv_rs,
                                                 float* __restrict__ isc)
{
  const int bh = blockIdx.y;
  const int b = bh >> 3;
  const int m = blockIdx.x * 256 + threadIdx.x;
  const float* ab = attn + (size_t)bh * NN * NN;
  const float* ir = inv_rs + bh * NN;
  const float cmv = colmask[b * NN + m];
  float acc = 0.f;
  for (int n = 0; n < NN; ++n) {
    const float v = ab[(size_t)n * NN + m];
    const float e = (cmv != 0.f || m == n) ? v : 0.f;
    acc += e * ir[n];
  }
  isc[bh * NN + m] = 1.0f / sqrtf(acc + 1e-16f);
}

// ---------------------------------------------------------------------------
// Gb[b,h,n,m] = bf16( mask(n,m)*attn[b,h,n,m] * inv_rs[b,h,n] * isc[b,h,m] )
// ---------------------------------------------------------------------------
__global__ __launch_bounds__(256) void g_kernel(const float* __restrict__ attn,
                                                const float* __restrict__ colmask,
                                                const float* __restrict__ inv_rs,
                                                const float* __restrict__ isc,
                                                __bf16* __restrict__ Gb)
{
  const size_t idx = ((size_t)blockIdx.x * 256 + threadIdx.x) << 2;
  const size_t row = idx >> 10;
  const int m = (int)(idx & 1023);
  const int n = (int)(row & 1023);
  const int bh = (int)(row >> 10);
  const int b = bh >> 3;
  const float4 v = *(const float4*)(attn + idx);
  const float4 c = *(const float4*)(colmask + b * NN + m);
  const float4 s = *(const float4*)(isc + bh * NN + m);
  const float ir = inv_rs[row];
  bf16x4 o;
  o.x = (__bf16)((((c.x != 0.f) || (m + 0 == n)) ? v.x : 0.f) * ir * s.x);
  o.y = (__bf16)((((c.y != 0.f) || (m + 1 == n)) ? v.y : 0.f) * ir * s.y);
  o.z = (__bf16)((((c.z != 0.f) || (m + 2 == n)) ? v.z : 0.f) * ir * s.z);
  o.w = (__bf16)((((c.w != 0.f) || (m + 3 == n)) ? v.w : 0.f) * ir * s.w);
  *(bf16x4*)(Gb + idx) = o;
}

// ---------------------------------------------------------------------------
// out[b,h] = Gb @ Gb^T via MFMA bf16 (f32 accumulate).
// 128x128 block tile, BK=32, 4 waves (2x2), 4x4 16x16x32 fragments per wave.
// global_load_lds width-16 staging, single LDS buffer, 2-barrier loop (m97).
// ---------------------------------------------------------------------------
__device__ inline void async16(const void* g, void* l)
{
  __builtin_amdgcn_global_load_lds(
      reinterpret_cast<const __attribute__((address_space(1))) unsigned int*>(
          reinterpret_cast<uintptr_t>(g)),
      reinterpret_cast<__attribute__((address_space(3))) unsigned int*>(
          reinterpret_cast<uintptr_t>(l)),
      16, 0, 0);
}

__global__ __launch_bounds__(256) void ggt_mfma_kernel(const __bf16* __restrict__ Gball,
                                                       float* __restrict__ outall)
{
  const int bh = blockIdx.z;
  const __bf16* A = Gball + ((size_t)bh << 20);   // [1024][1024] bf16
  float* C = outall + ((size_t)bh << 20);

  __shared__ __bf16 As[128 * 32];   // row-major [128][32], 64B rows
  __shared__ __bf16 Bs[128 * 32];

  const int tid  = threadIdx.x;
  const int lane = tid & 63;
  const int wid  = tid >> 6;
  const int wr   = wid >> 1;        // 0..1
  const int wc   = wid & 1;         // 0..1
  const int bM   = blockIdx.y * 128;
  const int bN   = blockIdx.x * 128;

  // staging: issue j in {0,1}; rows j*64 + wid*16 + lane/4, col (lane&3)*8
  const int srow = wid * 16 + (lane >> 2);
  const int scol = (lane & 3) * 8;
  const __bf16* gA = A + (size_t)(bM + srow) * NN + scol;
  const __bf16* gB = A + (size_t)(bN + srow) * NN + scol;
  char* lA = (char*)As + wid * 16 * 64;   // wave-uniform LDS base (bytes)
  char* lB = (char*)Bs + wid * 16 * 64;

  f32x4 acc[4][4];
  const f32x4 z = {0.f, 0.f, 0.f, 0.f};
#pragma unroll
  for (int m = 0; m < 4; ++m)
#pragma unroll
    for (int n = 0; n < 4; ++n) acc[m][n] = z;

  for (int k0 = 0; k0 < NN; k0 += 32) {
    async16(gA + k0,           lA);
    async16(gA + k0 + 64 * NN, lA + 64 * 64);
    async16(gB + k0,           lB);
    async16(gB + k0 + 64 * NN, lB + 64 * 64);
    __syncthreads();   // compiler drains vmcnt+lgkmcnt before barrier

    bf16x8 a[4], b[4];
#pragma unroll
    for (int m = 0; m < 4; ++m)
      a[m] = *(const bf16x8*)((const char*)As +
              (wr * 64 + m * 16 + (lane & 15)) * 64 + (lane >> 4) * 16);
#pragma unroll
    for (int n = 0; n < 4; ++n)
      b[n] = *(const bf16x8*)((const char*)Bs +
              (wc * 64 + n * 16 + (lane & 15)) * 64 + (lane >> 4) * 16);
#pragma unroll
    for (int m = 0; m < 4; ++m)
#pragma unroll
      for (int n = 0; n < 4; ++n)
        acc[m][n] = __builtin_amdgcn_mfma_f32_16x16x32_bf16(a[m], b[n], acc[m][n], 0, 0, 0);
    __syncthreads();
  }

  // C/D layout: col = lane&15, row = (lane>>4)*4 + reg
  const int fr = lane & 15;
  const int fq = lane >> 4;
#pragma unroll
  for (int m = 0; m < 4; ++m) {
    const int row0 = bM + wr * 64 + m * 16 + fq * 4;
#pragma unroll
    for (int n = 0; n < 4; ++n) {
      const int col = bN + wc * 64 + n * 16 + fr;
#pragma unroll
      for (int r = 0; r < 4; ++r)
        C[(size_t)(row0 + r) * NN + col] = acc[m][n][r];
    }
  }
}

// ---------------------------------------------------------------------------
extern "C" void kernel_launch(void* const* d_in, const int* in_sizes, int n_in,
                              void* d_out, int out_size, void* d_ws, size_t ws_size,
                              hipStream_t stream)
{
  const float* x = (const float*)d_in[0];   // [B,N,C]
  const float* W = (const float*)d_in[1];   // [2*H*C, C]
  float* attn = (float*)d_out;              // attn scratch, then final out
  char* ws = (char*)d_ws;

  const size_t G_BYTES = (size_t)BB * HH * NN * NN * 4;     // 268 MB region
  float*  qk    = (float*)(ws + 0);                         // [B*N, 4096]
  __bf16* Gb    = (__bf16*)(ws + 0);                        // [B,H,N,N] bf16 (134 MB)
  float*  se    = (float*)(ws + G_BYTES);                   // [B,N,N]
  float*  cmask = (float*)(ws + G_BYTES + (size_t)BB*NN*NN*4);
  float*  irs   = (float*)(ws + G_BYTES + (size_t)BB*NN*NN*4 + (size_t)BB*NN*4);
  float*  isc   = (float*)(ws + G_BYTES + (size_t)BB*NN*NN*4 + (size_t)BB*NN*4
                               + (size_t)BB*HH*NN*4);

  const long long HNN = (long long)HH * NN * NN, NN2 = (long long)NN * NN;

  // 1. qk = x @ W^T : [8192, 4096]
  hipLaunchKernelGGL(gemm_abt_kernel, dim3(OUTCH/64, (BB*NN)/64, 1), dim3(256), 0, stream,
                     x, W, qk, CC, CC, CC, OUTCH, 1,
                     0LL, 0LL, 0LL, 0LL, 0LL, 0LL, 1.0f);

  // 2. logits[b,h] = scale * q_bh @ k_bh^T  -> attn buffer (d_out)
  hipLaunchKernelGGL(gemm_abt_kernel, dim3(NN/64, NN/64, BB*HH), dim3(256), 0, stream,
                     qk, qk + 2048, attn, CC, OUTCH, OUTCH, NN, HH,
                     (long long)NN * OUTCH, 256LL,
                     (long long)NN * OUTCH, 256LL,
                     HNN, NN2, 0.0625f);

  // 3. softmax rows in place
  hipLaunchKernelGGL(softmax_kernel, dim3(BB*HH*NN), dim3(256), 0, stream, attn);

  // 4. sum over heads
  hipLaunchKernelGGL(sum_edge_kernel, dim3(BB*NN), dim3(256), 0, stream, attn, se);

  // 5. top-5 union -> column mask
  hipMemsetAsync(cmask, 0, (size_t)BB * NN * 4, stream);
  hipLaunchKernelGGL(topk_kernel, dim3(BB*NN), dim3(256), 0, stream, se, cmask);

  // 6. row sums (reciprocal)
  hipLaunchKernelGGL(rs_kernel, dim3(BB*HH*NN), dim3(256), 0, stream, attn, cmask, irs);

  // 7. column sums (inverse sqrt)
  hipLaunchKernelGGL(cs_kernel, dim3(NN/256, BB*HH), dim3(256), 0, stream,
                     attn, cmask, irs, isc);

  // 8. Gb = bf16( e * inv_rs * isc )
  hipLaunchKernelGGL(g_kernel, dim3((BB*HH*NN*(long long)NN) / 4 / 256), dim3(256), 0, stream,
                     attn, cmask, irs, isc, Gb);

  // 9. out[b,h] = Gb @ Gb^T  (MFMA, overwrites attn in d_out)
  hipLaunchKernelGGL(ggt_mfma_kernel, dim3(NN/128, NN/128, BB*HH), dim3(256), 0, stream,
                     Gb, attn);

  (void)in_sizes; (void)n_in; (void)out_size; (void)ws_size;
}

// Round 3
// 832.352 us; speedup vs baseline: 3.8108x; 1.7001x over previous
//
#include <hip/hip_runtime.h>
#include <hip/hip_bf16.h>
#include <cstdint>
#include <cstddef>

#define BB 8
#define HH 8
#define NN 1024
#define CC 256
#define OUTCH 4096   // 2*H*C

typedef __attribute__((ext_vector_type(8))) __bf16 bf16x8;
typedef __attribute__((ext_vector_type(4))) __bf16 bf16x4;
typedef __attribute__((ext_vector_type(4))) float f32x4;

// ---------------------------------------------------------------------------
// async global->LDS, 16B per lane, wave-uniform LDS base + lane*16
// ---------------------------------------------------------------------------
__device__ inline void async16(const void* g, void* l)
{
  __builtin_amdgcn_global_load_lds(
      reinterpret_cast<const __attribute__((address_space(1))) unsigned int*>(
          reinterpret_cast<uintptr_t>(g)),
      reinterpret_cast<__attribute__((address_space(3))) unsigned int*>(
          reinterpret_cast<uintptr_t>(l)),
      16, 0, 0);
}

// ---------------------------------------------------------------------------
// split f32 -> (hi, lo) bf16 planes
// ---------------------------------------------------------------------------
__global__ __launch_bounds__(256) void split_kernel(const float* __restrict__ in,
                                                    __bf16* __restrict__ hi,
                                                    __bf16* __restrict__ lo, int n4)
{
  const int i = blockIdx.x * 256 + threadIdx.x;
  if (i >= n4) return;
  const float4 v = ((const float4*)in)[i];
  bf16x4 h, l;
  h.x = (__bf16)v.x; l.x = (__bf16)(v.x - (float)h.x);
  h.y = (__bf16)v.y; l.y = (__bf16)(v.y - (float)h.y);
  h.z = (__bf16)v.z; l.z = (__bf16)(v.z - (float)h.z);
  h.w = (__bf16)v.w; l.w = (__bf16)(v.w - (float)h.w);
  ((bf16x4*)hi)[i] = h;
  ((bf16x4*)lo)[i] = l;
}

// ---------------------------------------------------------------------------
// Split-bf16 MFMA GEMM #1: qk = x @ W^T, written as hi/lo bf16 planes.
// A: [8192,256] (x hi/lo), B: [4096,256] (W hi/lo), C: [8192,4096].
// 128x128 tile, BK=32, 4 waves 2x2, 3 MFMA per fragment pair.
// ---------------------------------------------------------------------------
__global__ __launch_bounds__(256) void xw_mfma_kernel(
    const __bf16* __restrict__ Ah, const __bf16* __restrict__ Al,
    const __bf16* __restrict__ Bh, const __bf16* __restrict__ Bl,
    __bf16* __restrict__ Chi, __bf16* __restrict__ Clo)
{
  __shared__ __bf16 AsH[128 * 32], AsL[128 * 32], BsH[128 * 32], BsL[128 * 32];

  const int tid = threadIdx.x, lane = tid & 63, wid = tid >> 6;
  const int wr = wid >> 1, wc = wid & 1;
  const int bM = blockIdx.y * 128, bN = blockIdx.x * 128;

  const int srow = wid * 16 + (lane >> 2);
  const int scol = (lane & 3) * 8;
  const __bf16* gAh = Ah + (size_t)(bM + srow) * CC + scol;
  const __bf16* gAl = Al + (size_t)(bM + srow) * CC + scol;
  const __bf16* gBh = Bh + (size_t)(bN + srow) * CC + scol;
  const __bf16* gBl = Bl + (size_t)(bN + srow) * CC + scol;
  char* lAh = (char*)AsH + wid * 16 * 64;
  char* lAl = (char*)AsL + wid * 16 * 64;
  char* lBh = (char*)BsH + wid * 16 * 64;
  char* lBl = (char*)BsL + wid * 16 * 64;

  f32x4 acc[4][4];
  const f32x4 z = {0.f, 0.f, 0.f, 0.f};
#pragma unroll
  for (int m = 0; m < 4; ++m)
#pragma unroll
    for (int n = 0; n < 4; ++n) acc[m][n] = z;

  for (int k0 = 0; k0 < CC; k0 += 32) {
    async16(gAh + k0, lAh); async16(gAh + k0 + 64 * CC, lAh + 64 * 64);
    async16(gAl + k0, lAl); async16(gAl + k0 + 64 * CC, lAl + 64 * 64);
    async16(gBh + k0, lBh); async16(gBh + k0 + 64 * CC, lBh + 64 * 64);
    async16(gBl + k0, lBl); async16(gBl + k0 + 64 * CC, lBl + 64 * 64);
    __syncthreads();

    bf16x8 ah[4], al[4], bh_[4], bl_[4];
    const int fb = (lane & 15) * 64 + (lane >> 4) * 16;   // byte offset within row group
#pragma unroll
    for (int m = 0; m < 4; ++m) {
      ah[m] = *(const bf16x8*)((const char*)AsH + (wr * 64 + m * 16) * 64 + fb);
      al[m] = *(const bf16x8*)((const char*)AsL + (wr * 64 + m * 16) * 64 + fb);
    }
#pragma unroll
    for (int n = 0; n < 4; ++n) {
      bh_[n] = *(const bf16x8*)((const char*)BsH + (wc * 64 + n * 16) * 64 + fb);
      bl_[n] = *(const bf16x8*)((const char*)BsL + (wc * 64 + n * 16) * 64 + fb);
    }
#pragma unroll
    for (int m = 0; m < 4; ++m)
#pragma unroll
      for (int n = 0; n < 4; ++n) {
        acc[m][n] = __builtin_amdgcn_mfma_f32_16x16x32_bf16(al[m], bh_[n], acc[m][n], 0, 0, 0);
        acc[m][n] = __builtin_amdgcn_mfma_f32_16x16x32_bf16(ah[m], bl_[n], acc[m][n], 0, 0, 0);
        acc[m][n] = __builtin_amdgcn_mfma_f32_16x16x32_bf16(ah[m], bh_[n], acc[m][n], 0, 0, 0);
      }
    __syncthreads();
  }

  const int fr = lane & 15;
  const int fq = lane >> 4;
#pragma unroll
  for (int m = 0; m < 4; ++m) {
    const int row0 = bM + wr * 64 + m * 16 + fq * 4;
#pragma unroll
    for (int n = 0; n < 4; ++n) {
      const int col = bN + wc * 64 + n * 16 + fr;
#pragma unroll
      for (int r = 0; r < 4; ++r) {
        const float v = acc[m][n][r];
        const __bf16 h = (__bf16)v;
        const __bf16 l = (__bf16)(v - (float)h);
        Chi[(size_t)(row0 + r) * OUTCH + col] = h;
        Clo[(size_t)(row0 + r) * OUTCH + col] = l;
      }
    }
  }
}

// ---------------------------------------------------------------------------
// Split-bf16 MFMA GEMM #2: logits[b,h] = (1/16) * q_bh @ k_bh^T  -> f32
// q row n: plane + (b*N+n)*4096 + h*256 ; k adds +2048. K=256.
// ---------------------------------------------------------------------------
__global__ __launch_bounds__(256) void qkt_mfma_kernel(
    const __bf16* __restrict__ Qh, const __bf16* __restrict__ Ql,
    float* __restrict__ outall)
{
  const int bh = blockIdx.z;
  const int b = bh >> 3, h = bh & 7;
  const size_t qoff = (size_t)b * NN * OUTCH + (size_t)h * CC;
  const size_t koff = qoff + 2048;
  float* C = outall + ((size_t)bh << 20);

  __shared__ __bf16 AsH[128 * 32], AsL[128 * 32], BsH[128 * 32], BsL[128 * 32];

  const int tid = threadIdx.x, lane = tid & 63, wid = tid >> 6;
  const int wr = wid >> 1, wc = wid & 1;
  const int bM = blockIdx.y * 128, bN = blockIdx.x * 128;

  const int srow = wid * 16 + (lane >> 2);
  const int scol = (lane & 3) * 8;
  const __bf16* gAh = Qh + qoff + (size_t)(bM + srow) * OUTCH + scol;
  const __bf16* gAl = Ql + qoff + (size_t)(bM + srow) * OUTCH + scol;
  const __bf16* gBh = Qh + koff + (size_t)(bN + srow) * OUTCH + scol;
  const __bf16* gBl = Ql + koff + (size_t)(bN + srow) * OUTCH + scol;
  char* lAh = (char*)AsH + wid * 16 * 64;
  char* lAl = (char*)AsL + wid * 16 * 64;
  char* lBh = (char*)BsH + wid * 16 * 64;
  char* lBl = (char*)BsL + wid * 16 * 64;

  f32x4 acc[4][4];
  const f32x4 z = {0.f, 0.f, 0.f, 0.f};
#pragma unroll
  for (int m = 0; m < 4; ++m)
#pragma unroll
    for (int n = 0; n < 4; ++n) acc[m][n] = z;

  for (int k0 = 0; k0 < CC; k0 += 32) {
    async16(gAh + k0, lAh); async16(gAh + k0 + (size_t)64 * OUTCH, lAh + 64 * 64);
    async16(gAl + k0, lAl); async16(gAl + k0 + (size_t)64 * OUTCH, lAl + 64 * 64);
    async16(gBh + k0, lBh); async16(gBh + k0 + (size_t)64 * OUTCH, lBh + 64 * 64);
    async16(gBl + k0, lBl); async16(gBl + k0 + (size_t)64 * OUTCH, lBl + 64 * 64);
    __syncthreads();

    bf16x8 ah[4], al[4], bh_[4], bl_[4];
    const int fb = (lane & 15) * 64 + (lane >> 4) * 16;
#pragma unroll
    for (int m = 0; m < 4; ++m) {
      ah[m] = *(const bf16x8*)((const char*)AsH + (wr * 64 + m * 16) * 64 + fb);
      al[m] = *(const bf16x8*)((const char*)AsL + (wr * 64 + m * 16) * 64 + fb);
    }
#pragma unroll
    for (int n = 0; n < 4; ++n) {
      bh_[n] = *(const bf16x8*)((const char*)BsH + (wc * 64 + n * 16) * 64 + fb);
      bl_[n] = *(const bf16x8*)((const char*)BsL + (wc * 64 + n * 16) * 64 + fb);
    }
#pragma unroll
    for (int m = 0; m < 4; ++m)
#pragma unroll
      for (int n = 0; n < 4; ++n) {
        acc[m][n] = __builtin_amdgcn_mfma_f32_16x16x32_bf16(al[m], bh_[n], acc[m][n], 0, 0, 0);
        acc[m][n] = __builtin_amdgcn_mfma_f32_16x16x32_bf16(ah[m], bl_[n], acc[m][n], 0, 0, 0);
        acc[m][n] = __builtin_amdgcn_mfma_f32_16x16x32_bf16(ah[m], bh_[n], acc[m][n], 0, 0, 0);
      }
    __syncthreads();
  }

  const int fr = lane & 15;
  const int fq = lane >> 4;
#pragma unroll
  for (int m = 0; m < 4; ++m) {
    const int row0 = bM + wr * 64 + m * 16 + fq * 4;
#pragma unroll
    for (int n = 0; n < 4; ++n) {
      const int col = bN + wc * 64 + n * 16 + fr;
#pragma unroll
      for (int r = 0; r < 4; ++r)
        C[(size_t)(row0 + r) * NN + col] = acc[m][n][r] * 0.0625f;
    }
  }
}

// ---------------------------------------------------------------------------
// Fused: in-place row softmax for all 8 heads of one (b,n), plus
// se[b,n,:] = sum_h attn[b,h,n,:]
// ---------------------------------------------------------------------------
__global__ __launch_bounds__(256) void softmax_se_kernel(float* __restrict__ attn,
                                                         float* __restrict__ se)
{
  const int bn = blockIdx.x;
  const int b = bn >> 10;
  const int n = bn & 1023;
  const int t = threadIdx.x;
  __shared__ float red[256];
  float* base = attn + ((size_t)b * HH * NN + n) * NN;
  float4 acc = make_float4(0.f, 0.f, 0.f, 0.f);

#pragma unroll 1
  for (int h = 0; h < HH; ++h) {
    float* ar = base + (size_t)h * NN * NN;
    float4 x = *(float4*)(ar + (t << 2));
    float mx = fmaxf(fmaxf(x.x, x.y), fmaxf(x.z, x.w));
    red[t] = mx; __syncthreads();
    for (int s = 128; s > 0; s >>= 1) { if (t < s) red[t] = fmaxf(red[t], red[t+s]); __syncthreads(); }
    const float M = red[0]; __syncthreads();

    float e0 = expf(x.x - M), e1 = expf(x.y - M), e2 = expf(x.z - M), e3 = expf(x.w - M);
    red[t] = e0 + e1 + e2 + e3; __syncthreads();
    for (int s = 128; s > 0; s >>= 1) { if (t < s) red[t] += red[t+s]; __syncthreads(); }
    const float inv = 1.0f / red[0]; __syncthreads();

    float4 o; o.x = e0*inv; o.y = e1*inv; o.z = e2*inv; o.w = e3*inv;
    *(float4*)(ar + (t << 2)) = o;
    acc.x += o.x; acc.y += o.y; acc.z += o.z; acc.w += o.w;
  }
  *(float4*)(se + (size_t)bn * NN + (t << 2)) = acc;
}

// ---------------------------------------------------------------------------
// Top-5 per row of sum_edge; colmask[b, idx] = 1 for each winner.
// ---------------------------------------------------------------------------
__global__ __launch_bounds__(256) void topk_kernel(const float* __restrict__ se,
                                                   float* __restrict__ colmask)
{
  const int bn = blockIdx.x;
  const int b = bn >> 10;
  const int t = threadIdx.x;
  __shared__ float vals[NN];
  __shared__ unsigned long long red[256];
  const float* rowp = se + (size_t)bn * NN;
  for (int i = t; i < NN; i += 256) vals[i] = rowp[i];
  __syncthreads();

  for (int it = 0; it < 5; ++it) {
    unsigned long long best = 0ull;
    for (int i = t; i < NN; i += 256) {
      const float v = vals[i];
      if (v >= 0.f) {
        unsigned long long key =
            ((unsigned long long)__float_as_uint(v) << 32) | (unsigned)(NN - 1 - i);
        if (key > best) best = key;
      }
    }
    red[t] = best; __syncthreads();
    for (int s = 128; s > 0; s >>= 1) {
      if (t < s) red[t] = red[t] > red[t+s] ? red[t] : red[t+s];
      __syncthreads();
    }
    if (t == 0) {
      const int idx = NN - 1 - (int)(red[0] & 0xFFFFFFFFull);
      colmask[b * NN + idx] = 1.0f;
      vals[idx] = -1.0f;
    }
    __syncthreads();
  }
}

// ---------------------------------------------------------------------------
// inv_rs[b,h,n] = 1 / (sum_m mask(n,m)*attn[b,h,n,m] + 1e-16)
// ---------------------------------------------------------------------------
__global__ __launch_bounds__(256) void rs_kernel(const float* __restrict__ attn,
                                                 const float* __restrict__ colmask,
                                                 float* __restrict__ inv_rs)
{
  const int row = blockIdx.x;
  const int n = row & 1023;
  const int bh = row >> 10;
  const int b = bh >> 3;
  const int t = threadIdx.x;
  const float* ar = attn + (size_t)row * NN;
  const float* cm = colmask + b * NN;
  const int m = t << 2;
  const float4 v = *(const float4*)(ar + m);
  const float4 c = *(const float4*)(cm + m);
  float acc = 0.f;
  acc += ((c.x != 0.f) || (m + 0 == n)) ? v.x : 0.f;
  acc += ((c.y != 0.f) || (m + 1 == n)) ? v.y : 0.f;
  acc += ((c.z != 0.f) || (m + 2 == n)) ? v.z : 0.f;
  acc += ((c.w != 0.f) || (m + 3 == n)) ? v.w : 0.f;
  __shared__ float red[256];
  red[t] = acc; __syncthreads();
  for (int s = 128; s > 0; s >>= 1) { if (t < s) red[t] += red[t+s]; __syncthreads(); }
  if (t == 0) inv_rs[row] = 1.0f / (red[0] + 1e-16f);
}

// ---------------------------------------------------------------------------
// isc[b,h,m] = 1/sqrt( sum_n mask(n,m)*attn[b,h,n,m]*inv_rs[b,h,n] + 1e-16 )
// ---------------------------------------------------------------------------
__global__ __launch_bounds__(256) void cs_kernel(const float* __restrict__ attn,
                                                 const float* __restrict__ colmask,
                                                 const float* __restrict__ inv_rs,
                                                 float* __restrict__ isc)
{
  const int bh = blockIdx.y;
  const int b = bh >> 3;
  const int m = blockIdx.x * 256 + threadIdx.x;
  const float* ab = attn + (size_t)bh * NN * NN;
  const float* ir = inv_rs + bh * NN;
  const float cmv = colmask[b * NN + m];
  float acc = 0.f;
  for (int n = 0; n < NN; ++n) {
    const float v = ab[(size_t)n * NN + m];
    const float e = (cmv != 0.f || m == n) ? v : 0.f;
    acc += e * ir[n];
  }
  isc[bh * NN + m] = 1.0f / sqrtf(acc + 1e-16f);
}

// ---------------------------------------------------------------------------
// Gb[b,h,n,m] = bf16( mask(n,m)*attn[b,h,n,m] * inv_rs[b,h,n] * isc[b,h,m] )
// ---------------------------------------------------------------------------
__global__ __launch_bounds__(256) void g_kernel(const float* __restrict__ attn,
                                                const float* __restrict__ colmask,
                                                const float* __restrict__ inv_rs,
                                                const float* __restrict__ isc,
                                                __bf16* __restrict__ Gb)
{
  const size_t idx = ((size_t)blockIdx.x * 256 + threadIdx.x) << 2;
  const size_t row = idx >> 10;
  const int m = (int)(idx & 1023);
  const int n = (int)(row & 1023);
  const int bh = (int)(row >> 10);
  const int b = bh >> 3;
  const float4 v = *(const float4*)(attn + idx);
  const float4 c = *(const float4*)(colmask + b * NN + m);
  const float4 s = *(const float4*)(isc + bh * NN + m);
  const float ir = inv_rs[row];
  bf16x4 o;
  o.x = (__bf16)((((c.x != 0.f) || (m + 0 == n)) ? v.x : 0.f) * ir * s.x);
  o.y = (__bf16)((((c.y != 0.f) || (m + 1 == n)) ? v.y : 0.f) * ir * s.y);
  o.z = (__bf16)((((c.z != 0.f) || (m + 2 == n)) ? v.z : 0.f) * ir * s.z);
  o.w = (__bf16)((((c.w != 0.f) || (m + 3 == n)) ? v.w : 0.f) * ir * s.w);
  *(bf16x4*)(Gb + idx) = o;
}

// ---------------------------------------------------------------------------
// out[b,h] = Gb @ Gb^T via MFMA bf16 (f32 accumulate). m97-style 128x128.
// ---------------------------------------------------------------------------
__global__ __launch_bounds__(256) void ggt_mfma_kernel(const __bf16* __restrict__ Gball,
                                                       float* __restrict__ outall)
{
  const int bh = blockIdx.z;
  const __bf16* A = Gball + ((size_t)bh << 20);
  float* C = outall + ((size_t)bh << 20);

  __shared__ __bf16 As[128 * 32];
  __shared__ __bf16 Bs[128 * 32];

  const int tid  = threadIdx.x;
  const int lane = tid & 63;
  const int wid  = tid >> 6;
  const int wr   = wid >> 1;
  const int wc   = wid & 1;
  const int bM   = blockIdx.y * 128;
  const int bN   = blockIdx.x * 128;

  const int srow = wid * 16 + (lane >> 2);
  const int scol = (lane & 3) * 8;
  const __bf16* gA = A + (size_t)(bM + srow) * NN + scol;
  const __bf16* gB = A + (size_t)(bN + srow) * NN + scol;
  char* lA = (char*)As + wid * 16 * 64;
  char* lB = (char*)Bs + wid * 16 * 64;

  f32x4 acc[4][4];
  const f32x4 z = {0.f, 0.f, 0.f, 0.f};
#pragma unroll
  for (int m = 0; m < 4; ++m)
#pragma unroll
    for (int n = 0; n < 4; ++n) acc[m][n] = z;

  for (int k0 = 0; k0 < NN; k0 += 32) {
    async16(gA + k0,           lA);
    async16(gA + k0 + 64 * NN, lA + 64 * 64);
    async16(gB + k0,           lB);
    async16(gB + k0 + 64 * NN, lB + 64 * 64);
    __syncthreads();

    bf16x8 a[4], b[4];
    const int fb = (lane & 15) * 64 + (lane >> 4) * 16;
#pragma unroll
    for (int m = 0; m < 4; ++m)
      a[m] = *(const bf16x8*)((const char*)As + (wr * 64 + m * 16) * 64 + fb);
#pragma unroll
    for (int n = 0; n < 4; ++n)
      b[n] = *(const bf16x8*)((const char*)Bs + (wc * 64 + n * 16) * 64 + fb);
#pragma unroll
    for (int m = 0; m < 4; ++m)
#pragma unroll
      for (int n = 0; n < 4; ++n)
        acc[m][n] = __builtin_amdgcn_mfma_f32_16x16x32_bf16(a[m], b[n], acc[m][n], 0, 0, 0);
    __syncthreads();
  }

  const int fr = lane & 15;
  const int fq = lane >> 4;
#pragma unroll
  for (int m = 0; m < 4; ++m) {
    const int row0 = bM + wr * 64 + m * 16 + fq * 4;
#pragma unroll
    for (int n = 0; n < 4; ++n) {
      const int col = bN + wc * 64 + n * 16 + fr;
#pragma unroll
      for (int r = 0; r < 4; ++r)
        C[(size_t)(row0 + r) * NN + col] = acc[m][n][r];
    }
  }
}

// ---------------------------------------------------------------------------
extern "C" void kernel_launch(void* const* d_in, const int* in_sizes, int n_in,
                              void* d_out, int out_size, void* d_ws, size_t ws_size,
                              hipStream_t stream)
{
  const float* x = (const float*)d_in[0];   // [B,N,C]
  const float* W = (const float*)d_in[1];   // [2*H*C, C]
  float* attn = (float*)d_out;
  char* ws = (char*)d_ws;

  // workspace layout (MiB offsets). Gb (128 MiB at 0) reuses the dead
  // qk_hi/qk_lo region; x/W splits dead before Gb is written.
  __bf16* qk_hi = (__bf16*)(ws + ((size_t)0   << 20));   // 64 MiB
  __bf16* qk_lo = (__bf16*)(ws + ((size_t)64  << 20));   // 64 MiB
  __bf16* Gb    = (__bf16*)(ws + ((size_t)0   << 20));   // 128 MiB (reuse)
  __bf16* x_hi  = (__bf16*)(ws + ((size_t)128 << 20));   // 4 MiB
  __bf16* x_lo  = (__bf16*)(ws + ((size_t)132 << 20));   // 4 MiB
  __bf16* W_hi  = (__bf16*)(ws + ((size_t)136 << 20));   // 2 MiB
  __bf16* W_lo  = (__bf16*)(ws + ((size_t)138 << 20));   // 2 MiB
  float*  se    = (float*)(ws + ((size_t)144 << 20));    // 32 MiB
  float*  cmask = (float*)(ws + ((size_t)176 << 20));    // 32 KiB
  float*  irs   = (float*)(ws + ((size_t)177 << 20));    // 256 KiB
  float*  isc   = (float*)(ws + ((size_t)178 << 20));    // 256 KiB

  // 0. split x and W into bf16 hi/lo
  hipLaunchKernelGGL(split_kernel, dim3((BB*NN*CC/4 + 255)/256), dim3(256), 0, stream,
                     x, x_hi, x_lo, BB*NN*CC/4);
  hipLaunchKernelGGL(split_kernel, dim3((OUTCH*CC/4 + 255)/256), dim3(256), 0, stream,
                     W, W_hi, W_lo, OUTCH*CC/4);

  // 1. qk = x @ W^T (split-bf16 MFMA), output as hi/lo planes
  hipLaunchKernelGGL(xw_mfma_kernel, dim3(OUTCH/128, (BB*NN)/128, 1), dim3(256), 0, stream,
                     x_hi, x_lo, W_hi, W_lo, qk_hi, qk_lo);

  // 2. logits = scale * q @ k^T (split-bf16 MFMA) -> attn (d_out)
  hipLaunchKernelGGL(qkt_mfma_kernel, dim3(NN/128, NN/128, BB*HH), dim3(256), 0, stream,
                     qk_hi, qk_lo, attn);

  // 3+4. fused softmax rows + head-sum
  hipLaunchKernelGGL(softmax_se_kernel, dim3(BB*NN), dim3(256), 0, stream, attn, se);

  // 5. top-5 union -> column mask
  hipMemsetAsync(cmask, 0, (size_t)BB * NN * 4, stream);
  hipLaunchKernelGGL(topk_kernel, dim3(BB*NN), dim3(256), 0, stream, se, cmask);

  // 6. row sums
  hipLaunchKernelGGL(rs_kernel, dim3(BB*HH*NN), dim3(256), 0, stream, attn, cmask, irs);

  // 7. column sums
  hipLaunchKernelGGL(cs_kernel, dim3(NN/256, BB*HH), dim3(256), 0, stream,
                     attn, cmask, irs, isc);

  // 8. Gb = bf16( e * inv_rs * isc )
  hipLaunchKernelGGL(g_kernel, dim3((BB*HH*NN*(long long)NN) / 4 / 256), dim3(256), 0, stream,
                     attn, cmask, irs, isc, Gb);

  // 9. out = Gb @ Gb^T (MFMA)
  hipLaunchKernelGGL(ggt_mfma_kernel, dim3(NN/128, NN/128, BB*HH), dim3(256), 0, stream,
                     Gb, attn);

  (void)in_sizes; (void)n_in; (void)out_size; (void)ws_size;
}

// Round 4
// 720.125 us; speedup vs baseline: 4.4046x; 1.1558x over previous
//
#include <hip/hip_runtime.h>
#include <hip/hip_bf16.h>
#include <cstdint>
#include <cstddef>

#define BB 8
#define HH 8
#define NN 1024
#define CC 256
#define OUTCH 4096   // 2*H*C

typedef __attribute__((ext_vector_type(8))) __bf16 bf16x8;
typedef __attribute__((ext_vector_type(4))) __bf16 bf16x4;
typedef __attribute__((ext_vector_type(4))) float f32x4;

// ---------------------------------------------------------------------------
// async global->LDS, 16B per lane, wave-uniform LDS base + lane*16
// ---------------------------------------------------------------------------
__device__ inline void async16(const void* g, void* l)
{
  __builtin_amdgcn_global_load_lds(
      reinterpret_cast<const __attribute__((address_space(1))) unsigned int*>(
          reinterpret_cast<uintptr_t>(g)),
      reinterpret_cast<__attribute__((address_space(3))) unsigned int*>(
          reinterpret_cast<uintptr_t>(l)),
      16, 0, 0);
}

__device__ inline float waveMax(float v) {
#pragma unroll
  for (int o = 32; o > 0; o >>= 1) v = fmaxf(v, __shfl_xor(v, o, 64));
  return v;
}
__device__ inline float waveSum(float v) {
#pragma unroll
  for (int o = 32; o > 0; o >>= 1) v += __shfl_xor(v, o, 64);
  return v;
}

// ---------------------------------------------------------------------------
// split f32 -> (hi, lo) bf16 planes
// ---------------------------------------------------------------------------
__global__ __launch_bounds__(256) void split_kernel(const float* __restrict__ in,
                                                    __bf16* __restrict__ hi,
                                                    __bf16* __restrict__ lo, int n4)
{
  const int i = blockIdx.x * 256 + threadIdx.x;
  if (i >= n4) return;
  const float4 v = ((const float4*)in)[i];
  bf16x4 h, l;
  h.x = (__bf16)v.x; l.x = (__bf16)(v.x - (float)h.x);
  h.y = (__bf16)v.y; l.y = (__bf16)(v.y - (float)h.y);
  h.z = (__bf16)v.z; l.z = (__bf16)(v.z - (float)h.z);
  h.w = (__bf16)v.w; l.w = (__bf16)(v.w - (float)h.w);
  ((bf16x4*)hi)[i] = h;
  ((bf16x4*)lo)[i] = l;
}

// ---------------------------------------------------------------------------
// Split-bf16 MFMA GEMM #1: qk = x @ W^T, written as hi/lo bf16 planes.
// ---------------------------------------------------------------------------
__global__ __launch_bounds__(256) void xw_mfma_kernel(
    const __bf16* __restrict__ Ah, const __bf16* __restrict__ Al,
    const __bf16* __restrict__ Bh, const __bf16* __restrict__ Bl,
    __bf16* __restrict__ Chi, __bf16* __restrict__ Clo)
{
  __shared__ __bf16 AsH[128 * 32], AsL[128 * 32], BsH[128 * 32], BsL[128 * 32];

  const int tid = threadIdx.x, lane = tid & 63, wid = tid >> 6;
  const int wr = wid >> 1, wc = wid & 1;
  const int bM = blockIdx.y * 128, bN = blockIdx.x * 128;

  const int srow = wid * 16 + (lane >> 2);
  const int scol = (lane & 3) * 8;
  const __bf16* gAh = Ah + (size_t)(bM + srow) * CC + scol;
  const __bf16* gAl = Al + (size_t)(bM + srow) * CC + scol;
  const __bf16* gBh = Bh + (size_t)(bN + srow) * CC + scol;
  const __bf16* gBl = Bl + (size_t)(bN + srow) * CC + scol;
  char* lAh = (char*)AsH + wid * 16 * 64;
  char* lAl = (char*)AsL + wid * 16 * 64;
  char* lBh = (char*)BsH + wid * 16 * 64;
  char* lBl = (char*)BsL + wid * 16 * 64;

  f32x4 acc[4][4];
  const f32x4 z = {0.f, 0.f, 0.f, 0.f};
#pragma unroll
  for (int m = 0; m < 4; ++m)
#pragma unroll
    for (int n = 0; n < 4; ++n) acc[m][n] = z;

  for (int k0 = 0; k0 < CC; k0 += 32) {
    async16(gAh + k0, lAh); async16(gAh + k0 + 64 * CC, lAh + 64 * 64);
    async16(gAl + k0, lAl); async16(gAl + k0 + 64 * CC, lAl + 64 * 64);
    async16(gBh + k0, lBh); async16(gBh + k0 + 64 * CC, lBh + 64 * 64);
    async16(gBl + k0, lBl); async16(gBl + k0 + 64 * CC, lBl + 64 * 64);
    __syncthreads();

    bf16x8 ah[4], al[4], bh_[4], bl_[4];
    const int fb = (lane & 15) * 64 + (lane >> 4) * 16;
#pragma unroll
    for (int m = 0; m < 4; ++m) {
      ah[m] = *(const bf16x8*)((const char*)AsH + (wr * 64 + m * 16) * 64 + fb);
      al[m] = *(const bf16x8*)((const char*)AsL + (wr * 64 + m * 16) * 64 + fb);
    }
#pragma unroll
    for (int n = 0; n < 4; ++n) {
      bh_[n] = *(const bf16x8*)((const char*)BsH + (wc * 64 + n * 16) * 64 + fb);
      bl_[n] = *(const bf16x8*)((const char*)BsL + (wc * 64 + n * 16) * 64 + fb);
    }
#pragma unroll
    for (int m = 0; m < 4; ++m)
#pragma unroll
      for (int n = 0; n < 4; ++n) {
        acc[m][n] = __builtin_amdgcn_mfma_f32_16x16x32_bf16(al[m], bh_[n], acc[m][n], 0, 0, 0);
        acc[m][n] = __builtin_amdgcn_mfma_f32_16x16x32_bf16(ah[m], bl_[n], acc[m][n], 0, 0, 0);
        acc[m][n] = __builtin_amdgcn_mfma_f32_16x16x32_bf16(ah[m], bh_[n], acc[m][n], 0, 0, 0);
      }
    __syncthreads();
  }

  const int fr = lane & 15;
  const int fq = lane >> 4;
#pragma unroll
  for (int m = 0; m < 4; ++m) {
    const int row0 = bM + wr * 64 + m * 16 + fq * 4;
#pragma unroll
    for (int n = 0; n < 4; ++n) {
      const int col = bN + wc * 64 + n * 16 + fr;
#pragma unroll
      for (int r = 0; r < 4; ++r) {
        const float v = acc[m][n][r];
        const __bf16 h = (__bf16)v;
        const __bf16 l = (__bf16)(v - (float)h);
        Chi[(size_t)(row0 + r) * OUTCH + col] = h;
        Clo[(size_t)(row0 + r) * OUTCH + col] = l;
      }
    }
  }
}

// ---------------------------------------------------------------------------
// Split-bf16 MFMA GEMM #2: logits[b,h] = (1/16) * q_bh @ k_bh^T  -> f32
// ---------------------------------------------------------------------------
__global__ __launch_bounds__(256) void qkt_mfma_kernel(
    const __bf16* __restrict__ Qh, const __bf16* __restrict__ Ql,
    float* __restrict__ outall)
{
  const int bh = blockIdx.z;
  const int b = bh >> 3, h = bh & 7;
  const size_t qoff = (size_t)b * NN * OUTCH + (size_t)h * CC;
  const size_t koff = qoff + 2048;
  float* C = outall + ((size_t)bh << 20);

  __shared__ __bf16 AsH[128 * 32], AsL[128 * 32], BsH[128 * 32], BsL[128 * 32];

  const int tid = threadIdx.x, lane = tid & 63, wid = tid >> 6;
  const int wr = wid >> 1, wc = wid & 1;
  const int bM = blockIdx.y * 128, bN = blockIdx.x * 128;

  const int srow = wid * 16 + (lane >> 2);
  const int scol = (lane & 3) * 8;
  const __bf16* gAh = Qh + qoff + (size_t)(bM + srow) * OUTCH + scol;
  const __bf16* gAl = Ql + qoff + (size_t)(bM + srow) * OUTCH + scol;
  const __bf16* gBh = Qh + koff + (size_t)(bN + srow) * OUTCH + scol;
  const __bf16* gBl = Ql + koff + (size_t)(bN + srow) * OUTCH + scol;
  char* lAh = (char*)AsH + wid * 16 * 64;
  char* lAl = (char*)AsL + wid * 16 * 64;
  char* lBh = (char*)BsH + wid * 16 * 64;
  char* lBl = (char*)BsL + wid * 16 * 64;

  f32x4 acc[4][4];
  const f32x4 z = {0.f, 0.f, 0.f, 0.f};
#pragma unroll
  for (int m = 0; m < 4; ++m)
#pragma unroll
    for (int n = 0; n < 4; ++n) acc[m][n] = z;

  for (int k0 = 0; k0 < CC; k0 += 32) {
    async16(gAh + k0, lAh); async16(gAh + k0 + (size_t)64 * OUTCH, lAh + 64 * 64);
    async16(gAl + k0, lAl); async16(gAl + k0 + (size_t)64 * OUTCH, lAl + 64 * 64);
    async16(gBh + k0, lBh); async16(gBh + k0 + (size_t)64 * OUTCH, lBh + 64 * 64);
    async16(gBl + k0, lBl); async16(gBl + k0 + (size_t)64 * OUTCH, lBl + 64 * 64);
    __syncthreads();

    bf16x8 ah[4], al[4], bh_[4], bl_[4];
    const int fb = (lane & 15) * 64 + (lane >> 4) * 16;
#pragma unroll
    for (int m = 0; m < 4; ++m) {
      ah[m] = *(const bf16x8*)((const char*)AsH + (wr * 64 + m * 16) * 64 + fb);
      al[m] = *(const bf16x8*)((const char*)AsL + (wr * 64 + m * 16) * 64 + fb);
    }
#pragma unroll
    for (int n = 0; n < 4; ++n) {
      bh_[n] = *(const bf16x8*)((const char*)BsH + (wc * 64 + n * 16) * 64 + fb);
      bl_[n] = *(const bf16x8*)((const char*)BsL + (wc * 64 + n * 16) * 64 + fb);
    }
#pragma unroll
    for (int m = 0; m < 4; ++m)
#pragma unroll
      for (int n = 0; n < 4; ++n) {
        acc[m][n] = __builtin_amdgcn_mfma_f32_16x16x32_bf16(al[m], bh_[n], acc[m][n], 0, 0, 0);
        acc[m][n] = __builtin_amdgcn_mfma_f32_16x16x32_bf16(ah[m], bl_[n], acc[m][n], 0, 0, 0);
        acc[m][n] = __builtin_amdgcn_mfma_f32_16x16x32_bf16(ah[m], bh_[n], acc[m][n], 0, 0, 0);
      }
    __syncthreads();
  }

  const int fr = lane & 15;
  const int fq = lane >> 4;
#pragma unroll
  for (int m = 0; m < 4; ++m) {
    const int row0 = bM + wr * 64 + m * 16 + fq * 4;
#pragma unroll
    for (int n = 0; n < 4; ++n) {
      const int col = bN + wc * 64 + n * 16 + fr;
#pragma unroll
      for (int r = 0; r < 4; ++r)
        C[(size_t)(row0 + r) * NN + col] = acc[m][n][r] * 0.0625f;
    }
  }
}

// ---------------------------------------------------------------------------
// Fused softmax + head-sum. Reads f32 logits row, writes bf16 attn IN PLACE
// (bf16 row occupies first 2KB of the row's old 4KB f32 slot), se from f32.
// 3 barriers per head via wave-shuffle reductions.
// ---------------------------------------------------------------------------
__global__ __launch_bounds__(256) void softmax_se_kernel(float* __restrict__ attn,
                                                         float* __restrict__ se)
{
  const int bn = blockIdx.x;
  const int b = bn >> 10;
  const int n = bn & 1023;
  const int t = threadIdx.x;
  const int lane = t & 63, wv = t >> 6;
  __shared__ float wred[4];
  float* base = attn + ((size_t)b * HH * NN + n) * NN;
  __bf16* baseb = (__bf16*)base;                 // same bytes, bf16 row stride 2048
  float4 acc = make_float4(0.f, 0.f, 0.f, 0.f);

#pragma unroll 1
  for (int h = 0; h < HH; ++h) {
    float* ar = base + (size_t)h * NN * NN;
    __bf16* arb = baseb + (size_t)h * NN * NN * 2;
    float4 x = *(float4*)(ar + (t << 2));
    float mx = waveMax(fmaxf(fmaxf(x.x, x.y), fmaxf(x.z, x.w)));
    if (lane == 0) wred[wv] = mx;
    __syncthreads();                                       // (1)
    const float M = fmaxf(fmaxf(wred[0], wred[1]), fmaxf(wred[2], wred[3]));
    __syncthreads();                                       // (2) wred reusable

    float e0 = expf(x.x - M), e1 = expf(x.y - M), e2 = expf(x.z - M), e3 = expf(x.w - M);
    float s = waveSum(e0 + e1 + e2 + e3);
    if (lane == 0) wred[wv] = s;
    __syncthreads();                                       // (3) also orders reads<writes
    const float inv = 1.0f / (wred[0] + wred[1] + wred[2] + wred[3]);

    const float o0 = e0 * inv, o1 = e1 * inv, o2 = e2 * inv, o3 = e3 * inv;
    bf16x4 ob; ob.x = (__bf16)o0; ob.y = (__bf16)o1; ob.z = (__bf16)o2; ob.w = (__bf16)o3;
    *(bf16x4*)(arb + (t << 2)) = ob;
    acc.x += o0; acc.y += o1; acc.z += o2; acc.w += o3;
    __syncthreads();                                       // (4) wred safe for next head
  }
  *(float4*)(se + (size_t)bn * NN + (t << 2)) = acc;
}

// ---------------------------------------------------------------------------
// Top-5 per row of sum_edge; colmask[b, idx] = 1 for each winner.
// ---------------------------------------------------------------------------
__global__ __launch_bounds__(256) void topk_kernel(const float* __restrict__ se,
                                                   float* __restrict__ colmask)
{
  const int bn = blockIdx.x;
  const int b = bn >> 10;
  const int t = threadIdx.x;
  __shared__ float vals[NN];
  __shared__ unsigned long long red[256];
  const float* rowp = se + (size_t)bn * NN;
  for (int i = t; i < NN; i += 256) vals[i] = rowp[i];
  __syncthreads();

  for (int it = 0; it < 5; ++it) {
    unsigned long long best = 0ull;
    for (int i = t; i < NN; i += 256) {
      const float v = vals[i];
      if (v >= 0.f) {
        unsigned long long key =
            ((unsigned long long)__float_as_uint(v) << 32) | (unsigned)(NN - 1 - i);
        if (key > best) best = key;
      }
    }
    red[t] = best; __syncthreads();
    for (int s = 128; s > 0; s >>= 1) {
      if (t < s) red[t] = red[t] > red[t+s] ? red[t] : red[t+s];
      __syncthreads();
    }
    if (t == 0) {
      const int idx = NN - 1 - (int)(red[0] & 0xFFFFFFFFull);
      colmask[b * NN + idx] = 1.0f;
      vals[idx] = -1.0f;
    }
    __syncthreads();
  }
}

// ---------------------------------------------------------------------------
// inv_rs from bf16 attn (strided rows: 1024 bf16 payload, 2048 elem stride)
// ---------------------------------------------------------------------------
__global__ __launch_bounds__(256) void rs_kernel(const __bf16* __restrict__ attnb,
                                                 const float* __restrict__ colmask,
                                                 float* __restrict__ inv_rs)
{
  const int row = blockIdx.x;
  const int n = row & 1023;
  const int bh = row >> 10;
  const int b = bh >> 3;
  const int t = threadIdx.x;
  const int lane = t & 63, wv = t >> 6;
  const __bf16* ar = attnb + (size_t)row * 2048;
  const float* cm = colmask + b * NN;
  const int m = t << 2;
  const bf16x4 vb = *(const bf16x4*)(ar + m);
  const float4 c = *(const float4*)(cm + m);
  float acc = 0.f;
  acc += ((c.x != 0.f) || (m + 0 == n)) ? (float)vb.x : 0.f;
  acc += ((c.y != 0.f) || (m + 1 == n)) ? (float)vb.y : 0.f;
  acc += ((c.z != 0.f) || (m + 2 == n)) ? (float)vb.z : 0.f;
  acc += ((c.w != 0.f) || (m + 3 == n)) ? (float)vb.w : 0.f;
  acc = waveSum(acc);
  __shared__ float wred[4];
  if (lane == 0) wred[wv] = acc;
  __syncthreads();
  if (t == 0) inv_rs[row] = 1.0f / (wred[0] + wred[1] + wred[2] + wred[3] + 1e-16f);
}

// ---------------------------------------------------------------------------
// isc[b,h,m] from bf16 attn. Grid (1, B*H); thread owns 4 columns.
// ---------------------------------------------------------------------------
__global__ __launch_bounds__(256) void cs_kernel(const __bf16* __restrict__ attnb,
                                                 const float* __restrict__ colmask,
                                                 const float* __restrict__ inv_rs,
                                                 float* __restrict__ isc)
{
  const int bh = blockIdx.y;
  const int b = bh >> 3;
  const int m0 = threadIdx.x << 2;
  const __bf16* ab = attnb + (size_t)bh * NN * 2048;
  const float* ir = inv_rs + bh * NN;
  const float4 cm = *(const float4*)(colmask + b * NN + m0);
  float a0 = 0.f, a1 = 0.f, a2 = 0.f, a3 = 0.f;
  for (int n = 0; n < NN; ++n) {
    const bf16x4 vb = *(const bf16x4*)(ab + (size_t)n * 2048 + m0);
    const float w = ir[n];
    a0 += ((cm.x != 0.f) || (m0 + 0 == n)) ? (float)vb.x * w : 0.f;
    a1 += ((cm.y != 0.f) || (m0 + 1 == n)) ? (float)vb.y * w : 0.f;
    a2 += ((cm.z != 0.f) || (m0 + 2 == n)) ? (float)vb.z * w : 0.f;
    a3 += ((cm.w != 0.f) || (m0 + 3 == n)) ? (float)vb.w * w : 0.f;
  }
  float4 o;
  o.x = 1.0f / sqrtf(a0 + 1e-16f);
  o.y = 1.0f / sqrtf(a1 + 1e-16f);
  o.z = 1.0f / sqrtf(a2 + 1e-16f);
  o.w = 1.0f / sqrtf(a3 + 1e-16f);
  *(float4*)(isc + bh * NN + m0) = o;
}

// ---------------------------------------------------------------------------
// Gb[b,h,n,m] = bf16( e * inv_rs[n] * isc[m] ), e from bf16 attn. Contiguous out.
// ---------------------------------------------------------------------------
__global__ __launch_bounds__(256) void g_kernel(const __bf16* __restrict__ attnb,
                                                const float* __restrict__ colmask,
                                                const float* __restrict__ inv_rs,
                                                const float* __restrict__ isc,
                                                __bf16* __restrict__ Gb)
{
  const size_t idx = ((size_t)blockIdx.x * 256 + threadIdx.x) << 2;
  const size_t row = idx >> 10;
  const int m = (int)(idx & 1023);
  const int n = (int)(row & 1023);
  const int bh = (int)(row >> 10);
  const int b = bh >> 3;
  const bf16x4 vb = *(const bf16x4*)(attnb + row * 2048 + m);
  const float4 c = *(const float4*)(colmask + b * NN + m);
  const float4 s = *(const float4*)(isc + bh * NN + m);
  const float ir = inv_rs[row];
  bf16x4 o;
  o.x = (__bf16)((((c.x != 0.f) || (m + 0 == n)) ? (float)vb.x : 0.f) * ir * s.x);
  o.y = (__bf16)((((c.y != 0.f) || (m + 1 == n)) ? (float)vb.y : 0.f) * ir * s.y);
  o.z = (__bf16)((((c.z != 0.f) || (m + 2 == n)) ? (float)vb.z : 0.f) * ir * s.z);
  o.w = (__bf16)((((c.w != 0.f) || (m + 3 == n)) ? (float)vb.w : 0.f) * ir * s.w);
  *(bf16x4*)(Gb + idx) = o;
}

// ---------------------------------------------------------------------------
// out[b,h] = Gb @ Gb^T (symmetric): only upper-triangle 128x128 tiles computed;
// off-diagonal tiles written twice (normal + transposed, both coalesced).
// ---------------------------------------------------------------------------
__global__ __launch_bounds__(256) void ggt_mfma_kernel(const __bf16* __restrict__ Gball,
                                                       float* __restrict__ outall)
{
  const int bh = blockIdx.z;
  const __bf16* A = Gball + ((size_t)bh << 20);
  float* C = outall + ((size_t)bh << 20);

  // decode triangular tile index -> (ti, tj), ti <= tj, 8x8 tile grid
  int tt = blockIdx.x;
  int ti = 0;
#pragma unroll
  for (int r = 0; r < 8; ++r) {
    const int len = 8 - r;
    if (tt < len) { ti = r; break; }
    tt -= len;
  }
  const int tj = ti + tt;

  __shared__ __bf16 As[128 * 32];
  __shared__ __bf16 Bs[128 * 32];

  const int tid  = threadIdx.x;
  const int lane = tid & 63;
  const int wid  = tid >> 6;
  const int wr   = wid >> 1;
  const int wc   = wid & 1;
  const int bM   = ti * 128;
  const int bN   = tj * 128;

  const int srow = wid * 16 + (lane >> 2);
  const int scol = (lane & 3) * 8;
  const __bf16* gA = A + (size_t)(bM + srow) * NN + scol;
  const __bf16* gB = A + (size_t)(bN + srow) * NN + scol;
  char* lA = (char*)As + wid * 16 * 64;
  char* lB = (char*)Bs + wid * 16 * 64;

  f32x4 acc[4][4];
  const f32x4 z = {0.f, 0.f, 0.f, 0.f};
#pragma unroll
  for (int m = 0; m < 4; ++m)
#pragma unroll
    for (int n = 0; n < 4; ++n) acc[m][n] = z;

  for (int k0 = 0; k0 < NN; k0 += 32) {
    async16(gA + k0,           lA);
    async16(gA + k0 + 64 * NN, lA + 64 * 64);
    async16(gB + k0,           lB);
    async16(gB + k0 + 64 * NN, lB + 64 * 64);
    __syncthreads();

    bf16x8 a[4], b[4];
    const int fb = (lane & 15) * 64 + (lane >> 4) * 16;
#pragma unroll
    for (int m = 0; m < 4; ++m)
      a[m] = *(const bf16x8*)((const char*)As + (wr * 64 + m * 16) * 64 + fb);
#pragma unroll
    for (int n = 0; n < 4; ++n)
      b[n] = *(const bf16x8*)((const char*)Bs + (wc * 64 + n * 16) * 64 + fb);
#pragma unroll
    for (int m = 0; m < 4; ++m)
#pragma unroll
      for (int n = 0; n < 4; ++n)
        acc[m][n] = __builtin_amdgcn_mfma_f32_16x16x32_bf16(a[m], b[n], acc[m][n], 0, 0, 0);
    __syncthreads();
  }

  const int fr = lane & 15;
  const int fq = lane >> 4;
  // normal write: C[bM.., bN..]
#pragma unroll
  for (int m = 0; m < 4; ++m) {
    const int row0 = bM + wr * 64 + m * 16 + fq * 4;
#pragma unroll
    for (int n = 0; n < 4; ++n) {
      const int col = bN + wc * 64 + n * 16 + fr;
#pragma unroll
      for (int r = 0; r < 4; ++r)
        C[(size_t)(row0 + r) * NN + col] = acc[m][n][r];
    }
  }
  // mirrored write: C[bN.., bM..] = tile^T (per-lane contiguous float4)
  if (ti != tj) {
#pragma unroll
    for (int m = 0; m < 4; ++m) {
      const int colT = bM + wr * 64 + m * 16 + fq * 4;
#pragma unroll
      for (int n = 0; n < 4; ++n) {
        const int rowT = bN + wc * 64 + n * 16 + fr;
        *(f32x4*)(C + (size_t)rowT * NN + colT) = acc[m][n];
      }
    }
  }
}

// ---------------------------------------------------------------------------
extern "C" void kernel_launch(void* const* d_in, const int* in_sizes, int n_in,
                              void* d_out, int out_size, void* d_ws, size_t ws_size,
                              hipStream_t stream)
{
  const float* x = (const float*)d_in[0];   // [B,N,C]
  const float* W = (const float*)d_in[1];   // [2*H*C, C]
  float* attn = (float*)d_out;              // f32 logits -> bf16 attn (in place) -> final out
  __bf16* attnb = (__bf16*)d_out;           // bf16 rows, stride 2048 elems
  char* ws = (char*)d_ws;

  __bf16* qk_hi = (__bf16*)(ws + ((size_t)0   << 20));   // 64 MiB
  __bf16* qk_lo = (__bf16*)(ws + ((size_t)64  << 20));   // 64 MiB
  __bf16* Gb    = (__bf16*)(ws + ((size_t)0   << 20));   // 128 MiB (reuses qk)
  __bf16* x_hi  = (__bf16*)(ws + ((size_t)128 << 20));
  __bf16* x_lo  = (__bf16*)(ws + ((size_t)132 << 20));
  __bf16* W_hi  = (__bf16*)(ws + ((size_t)136 << 20));
  __bf16* W_lo  = (__bf16*)(ws + ((size_t)138 << 20));
  float*  se    = (float*)(ws + ((size_t)144 << 20));    // 32 MiB
  float*  cmask = (float*)(ws + ((size_t)176 << 20));
  float*  irs   = (float*)(ws + ((size_t)177 << 20));
  float*  isc   = (float*)(ws + ((size_t)178 << 20));

  // 0. split x and W into bf16 hi/lo
  hipLaunchKernelGGL(split_kernel, dim3((BB*NN*CC/4 + 255)/256), dim3(256), 0, stream,
                     x, x_hi, x_lo, BB*NN*CC/4);
  hipLaunchKernelGGL(split_kernel, dim3((OUTCH*CC/4 + 255)/256), dim3(256), 0, stream,
                     W, W_hi, W_lo, OUTCH*CC/4);

  // 1. qk = x @ W^T (split-bf16 MFMA)
  hipLaunchKernelGGL(xw_mfma_kernel, dim3(OUTCH/128, (BB*NN)/128, 1), dim3(256), 0, stream,
                     x_hi, x_lo, W_hi, W_lo, qk_hi, qk_lo);

  // 2. logits = scale * q @ k^T -> d_out (f32)
  hipLaunchKernelGGL(qkt_mfma_kernel, dim3(NN/128, NN/128, BB*HH), dim3(256), 0, stream,
                     qk_hi, qk_lo, attn);

  // 3+4. softmax (f32 in, bf16 out in place) + head-sum (f32)
  hipLaunchKernelGGL(softmax_se_kernel, dim3(BB*NN), dim3(256), 0, stream, attn, se);

  // 5. top-5 union -> column mask
  hipMemsetAsync(cmask, 0, (size_t)BB * NN * 4, stream);
  hipLaunchKernelGGL(topk_kernel, dim3(BB*NN), dim3(256), 0, stream, se, cmask);

  // 6. row sums
  hipLaunchKernelGGL(rs_kernel, dim3(BB*HH*NN), dim3(256), 0, stream, attnb, cmask, irs);

  // 7. column sums
  hipLaunchKernelGGL(cs_kernel, dim3(1, BB*HH), dim3(256), 0, stream,
                     attnb, cmask, irs, isc);

  // 8. Gb = bf16( e * inv_rs * isc )
  hipLaunchKernelGGL(g_kernel, dim3((BB*HH*NN*(long long)NN) / 4 / 256), dim3(256), 0, stream,
                     attnb, cmask, irs, isc, Gb);

  // 9. out = Gb @ Gb^T (symmetric MFMA) -> d_out f32
  hipLaunchKernelGGL(ggt_mfma_kernel, dim3(36, 1, BB*HH), dim3(256), 0, stream,
                     Gb, attn);

  (void)in_sizes; (void)n_in; (void)out_size; (void)ws_size;
}

// Round 5
// 586.322 us; speedup vs baseline: 5.4098x; 1.2282x over previous
//
#include <hip/hip_runtime.h>
#include <hip/hip_bf16.h>
#include <cstdint>
#include <cstddef>

#define BB 8
#define HH 8
#define NN 1024
#define CC 256
#define OUTCH 4096   // 2*H*C

typedef __attribute__((ext_vector_type(8))) __bf16 bf16x8;
typedef __attribute__((ext_vector_type(4))) __bf16 bf16x4;
typedef __attribute__((ext_vector_type(4))) float f32x4;

// ---------------------------------------------------------------------------
// async global->LDS, 16B per lane, wave-uniform LDS base + lane*16
// ---------------------------------------------------------------------------
__device__ inline void async16(const void* g, void* l)
{
  __builtin_amdgcn_global_load_lds(
      reinterpret_cast<const __attribute__((address_space(1))) unsigned int*>(
          reinterpret_cast<uintptr_t>(g)),
      reinterpret_cast<__attribute__((address_space(3))) unsigned int*>(
          reinterpret_cast<uintptr_t>(l)),
      16, 0, 0);
}

__device__ inline float waveMax(float v) {
#pragma unroll
  for (int o = 32; o > 0; o >>= 1) v = fmaxf(v, __shfl_xor(v, o, 64));
  return v;
}
__device__ inline float waveSum(float v) {
#pragma unroll
  for (int o = 32; o > 0; o >>= 1) v += __shfl_xor(v, o, 64);
  return v;
}

// ---------------------------------------------------------------------------
// split f32 -> (hi, lo) bf16 planes
// ---------------------------------------------------------------------------
__global__ __launch_bounds__(256) void split_kernel(const float* __restrict__ in,
                                                    __bf16* __restrict__ hi,
                                                    __bf16* __restrict__ lo, int n4)
{
  const int i = blockIdx.x * 256 + threadIdx.x;
  if (i >= n4) return;
  const float4 v = ((const float4*)in)[i];
  bf16x4 h, l;
  h.x = (__bf16)v.x; l.x = (__bf16)(v.x - (float)h.x);
  h.y = (__bf16)v.y; l.y = (__bf16)(v.y - (float)h.y);
  h.z = (__bf16)v.z; l.z = (__bf16)(v.z - (float)h.z);
  h.w = (__bf16)v.w; l.w = (__bf16)(v.w - (float)h.w);
  ((bf16x4*)hi)[i] = h;
  ((bf16x4*)lo)[i] = l;
}

// ---------------------------------------------------------------------------
// Split-bf16 MFMA GEMM #1: qk = x @ W^T, written as hi/lo bf16 planes.
// ---------------------------------------------------------------------------
__global__ __launch_bounds__(256) void xw_mfma_kernel(
    const __bf16* __restrict__ Ah, const __bf16* __restrict__ Al,
    const __bf16* __restrict__ Bh, const __bf16* __restrict__ Bl,
    __bf16* __restrict__ Chi, __bf16* __restrict__ Clo)
{
  __shared__ __bf16 AsH[128 * 32], AsL[128 * 32], BsH[128 * 32], BsL[128 * 32];

  const int tid = threadIdx.x, lane = tid & 63, wid = tid >> 6;
  const int wr = wid >> 1, wc = wid & 1;
  const int bM = blockIdx.y * 128, bN = blockIdx.x * 128;

  const int srow = wid * 16 + (lane >> 2);
  const int scol = (lane & 3) * 8;
  const __bf16* gAh = Ah + (size_t)(bM + srow) * CC + scol;
  const __bf16* gAl = Al + (size_t)(bM + srow) * CC + scol;
  const __bf16* gBh = Bh + (size_t)(bN + srow) * CC + scol;
  const __bf16* gBl = Bl + (size_t)(bN + srow) * CC + scol;
  char* lAh = (char*)AsH + wid * 16 * 64;
  char* lAl = (char*)AsL + wid * 16 * 64;
  char* lBh = (char*)BsH + wid * 16 * 64;
  char* lBl = (char*)BsL + wid * 16 * 64;

  f32x4 acc[4][4];
  const f32x4 z = {0.f, 0.f, 0.f, 0.f};
#pragma unroll
  for (int m = 0; m < 4; ++m)
#pragma unroll
    for (int n = 0; n < 4; ++n) acc[m][n] = z;

  for (int k0 = 0; k0 < CC; k0 += 32) {
    async16(gAh + k0, lAh); async16(gAh + k0 + 64 * CC, lAh + 64 * 64);
    async16(gAl + k0, lAl); async16(gAl + k0 + 64 * CC, lAl + 64 * 64);
    async16(gBh + k0, lBh); async16(gBh + k0 + 64 * CC, lBh + 64 * 64);
    async16(gBl + k0, lBl); async16(gBl + k0 + 64 * CC, lBl + 64 * 64);
    __syncthreads();

    bf16x8 ah[4], al[4], bh_[4], bl_[4];
    const int fb = (lane & 15) * 64 + (lane >> 4) * 16;
#pragma unroll
    for (int m = 0; m < 4; ++m) {
      ah[m] = *(const bf16x8*)((const char*)AsH + (wr * 64 + m * 16) * 64 + fb);
      al[m] = *(const bf16x8*)((const char*)AsL + (wr * 64 + m * 16) * 64 + fb);
    }
#pragma unroll
    for (int n = 0; n < 4; ++n) {
      bh_[n] = *(const bf16x8*)((const char*)BsH + (wc * 64 + n * 16) * 64 + fb);
      bl_[n] = *(const bf16x8*)((const char*)BsL + (wc * 64 + n * 16) * 64 + fb);
    }
#pragma unroll
    for (int m = 0; m < 4; ++m)
#pragma unroll
      for (int n = 0; n < 4; ++n) {
        acc[m][n] = __builtin_amdgcn_mfma_f32_16x16x32_bf16(al[m], bh_[n], acc[m][n], 0, 0, 0);
        acc[m][n] = __builtin_amdgcn_mfma_f32_16x16x32_bf16(ah[m], bl_[n], acc[m][n], 0, 0, 0);
        acc[m][n] = __builtin_amdgcn_mfma_f32_16x16x32_bf16(ah[m], bh_[n], acc[m][n], 0, 0, 0);
      }
    __syncthreads();
  }

  const int fr = lane & 15;
  const int fq = lane >> 4;
#pragma unroll
  for (int m = 0; m < 4; ++m) {
    const int row0 = bM + wr * 64 + m * 16 + fq * 4;
#pragma unroll
    for (int n = 0; n < 4; ++n) {
      const int col = bN + wc * 64 + n * 16 + fr;
#pragma unroll
      for (int r = 0; r < 4; ++r) {
        const float v = acc[m][n][r];
        const __bf16 h = (__bf16)v;
        const __bf16 l = (__bf16)(v - (float)h);
        Chi[(size_t)(row0 + r) * OUTCH + col] = h;
        Clo[(size_t)(row0 + r) * OUTCH + col] = l;
      }
    }
  }
}

// ---------------------------------------------------------------------------
// Split-bf16 MFMA GEMM #2: logits[b,h] = (1/16) * q_bh @ k_bh^T  -> f32
// 1D grid, bh-resident XCD swizzle: f = (bh%8) + 8*((bh/8)*64 + tile)
// ---------------------------------------------------------------------------
__global__ __launch_bounds__(256) void qkt_mfma_kernel(
    const __bf16* __restrict__ Qh, const __bf16* __restrict__ Ql,
    float* __restrict__ outall)
{
  const int f = blockIdx.x;
  const int xcd = f & 7;
  const int g = f >> 3;            // (bh/8)*64 + tile
  const int bh = xcd + 8 * (g >> 6);
  const int tile = g & 63;
  const int b = bh >> 3, h = bh & 7;
  const size_t qoff = (size_t)b * NN * OUTCH + (size_t)h * CC;
  const size_t koff = qoff + 2048;
  float* C = outall + ((size_t)bh << 20);

  __shared__ __bf16 AsH[128 * 32], AsL[128 * 32], BsH[128 * 32], BsL[128 * 32];

  const int tid = threadIdx.x, lane = tid & 63, wid = tid >> 6;
  const int wr = wid >> 1, wc = wid & 1;
  const int bM = (tile >> 3) * 128, bN = (tile & 7) * 128;

  const int srow = wid * 16 + (lane >> 2);
  const int scol = (lane & 3) * 8;
  const __bf16* gAh = Qh + qoff + (size_t)(bM + srow) * OUTCH + scol;
  const __bf16* gAl = Ql + qoff + (size_t)(bM + srow) * OUTCH + scol;
  const __bf16* gBh = Qh + koff + (size_t)(bN + srow) * OUTCH + scol;
  const __bf16* gBl = Ql + koff + (size_t)(bN + srow) * OUTCH + scol;
  char* lAh = (char*)AsH + wid * 16 * 64;
  char* lAl = (char*)AsL + wid * 16 * 64;
  char* lBh = (char*)BsH + wid * 16 * 64;
  char* lBl = (char*)BsL + wid * 16 * 64;

  f32x4 acc[4][4];
  const f32x4 z = {0.f, 0.f, 0.f, 0.f};
#pragma unroll
  for (int m = 0; m < 4; ++m)
#pragma unroll
    for (int n = 0; n < 4; ++n) acc[m][n] = z;

  for (int k0 = 0; k0 < CC; k0 += 32) {
    async16(gAh + k0, lAh); async16(gAh + k0 + (size_t)64 * OUTCH, lAh + 64 * 64);
    async16(gAl + k0, lAl); async16(gAl + k0 + (size_t)64 * OUTCH, lAl + 64 * 64);
    async16(gBh + k0, lBh); async16(gBh + k0 + (size_t)64 * OUTCH, lBh + 64 * 64);
    async16(gBl + k0, lBl); async16(gBl + k0 + (size_t)64 * OUTCH, lBl + 64 * 64);
    __syncthreads();

    bf16x8 ah[4], al[4], bh_[4], bl_[4];
    const int fb = (lane & 15) * 64 + (lane >> 4) * 16;
#pragma unroll
    for (int m = 0; m < 4; ++m) {
      ah[m] = *(const bf16x8*)((const char*)AsH + (wr * 64 + m * 16) * 64 + fb);
      al[m] = *(const bf16x8*)((const char*)AsL + (wr * 64 + m * 16) * 64 + fb);
    }
#pragma unroll
    for (int n = 0; n < 4; ++n) {
      bh_[n] = *(const bf16x8*)((const char*)BsH + (wc * 64 + n * 16) * 64 + fb);
      bl_[n] = *(const bf16x8*)((const char*)BsL + (wc * 64 + n * 16) * 64 + fb);
    }
#pragma unroll
    for (int m = 0; m < 4; ++m)
#pragma unroll
      for (int n = 0; n < 4; ++n) {
        acc[m][n] = __builtin_amdgcn_mfma_f32_16x16x32_bf16(al[m], bh_[n], acc[m][n], 0, 0, 0);
        acc[m][n] = __builtin_amdgcn_mfma_f32_16x16x32_bf16(ah[m], bl_[n], acc[m][n], 0, 0, 0);
        acc[m][n] = __builtin_amdgcn_mfma_f32_16x16x32_bf16(ah[m], bh_[n], acc[m][n], 0, 0, 0);
      }
    __syncthreads();
  }

  const int fr = lane & 15;
  const int fq = lane >> 4;
#pragma unroll
  for (int m = 0; m < 4; ++m) {
    const int row0 = bM + wr * 64 + m * 16 + fq * 4;
#pragma unroll
    for (int n = 0; n < 4; ++n) {
      const int col = bN + wc * 64 + n * 16 + fr;
#pragma unroll
      for (int r = 0; r < 4; ++r)
        C[(size_t)(row0 + r) * NN + col] = acc[m][n][r] * 0.0625f;
    }
  }
}

// ---------------------------------------------------------------------------
// Fused softmax + head-sum. f32 logits in, bf16 attn out IN PLACE.
// ---------------------------------------------------------------------------
__global__ __launch_bounds__(256) void softmax_se_kernel(float* __restrict__ attn,
                                                         float* __restrict__ se)
{
  const int bn = blockIdx.x;
  const int b = bn >> 10;
  const int n = bn & 1023;
  const int t = threadIdx.x;
  const int lane = t & 63, wv = t >> 6;
  __shared__ float wred[4];
  float* base = attn + ((size_t)b * HH * NN + n) * NN;
  __bf16* baseb = (__bf16*)base;
  float4 acc = make_float4(0.f, 0.f, 0.f, 0.f);

#pragma unroll 1
  for (int h = 0; h < HH; ++h) {
    float* ar = base + (size_t)h * NN * NN;
    __bf16* arb = baseb + (size_t)h * NN * NN * 2;
    float4 x = *(float4*)(ar + (t << 2));
    float mx = waveMax(fmaxf(fmaxf(x.x, x.y), fmaxf(x.z, x.w)));
    if (lane == 0) wred[wv] = mx;
    __syncthreads();
    const float M = fmaxf(fmaxf(wred[0], wred[1]), fmaxf(wred[2], wred[3]));
    __syncthreads();

    float e0 = expf(x.x - M), e1 = expf(x.y - M), e2 = expf(x.z - M), e3 = expf(x.w - M);
    float s = waveSum(e0 + e1 + e2 + e3);
    if (lane == 0) wred[wv] = s;
    __syncthreads();
    const float inv = 1.0f / (wred[0] + wred[1] + wred[2] + wred[3]);

    const float o0 = e0 * inv, o1 = e1 * inv, o2 = e2 * inv, o3 = e3 * inv;
    bf16x4 ob; ob.x = (__bf16)o0; ob.y = (__bf16)o1; ob.z = (__bf16)o2; ob.w = (__bf16)o3;
    *(bf16x4*)(arb + (t << 2)) = ob;
    acc.x += o0; acc.y += o1; acc.z += o2; acc.w += o3;
    __syncthreads();
  }
  *(float4*)(se + (size_t)bn * NN + (t << 2)) = acc;
}

// ---------------------------------------------------------------------------
// Top-5 per row of sum_edge; colmask[b, idx] = 1 for each winner.
// ---------------------------------------------------------------------------
__global__ __launch_bounds__(256) void topk_kernel(const float* __restrict__ se,
                                                   float* __restrict__ colmask)
{
  const int bn = blockIdx.x;
  const int b = bn >> 10;
  const int t = threadIdx.x;
  __shared__ float vals[NN];
  __shared__ unsigned long long red[256];
  const float* rowp = se + (size_t)bn * NN;
  for (int i = t; i < NN; i += 256) vals[i] = rowp[i];
  __syncthreads();

  for (int it = 0; it < 5; ++it) {
    unsigned long long best = 0ull;
    for (int i = t; i < NN; i += 256) {
      const float v = vals[i];
      if (v >= 0.f) {
        unsigned long long key =
            ((unsigned long long)__float_as_uint(v) << 32) | (unsigned)(NN - 1 - i);
        if (key > best) best = key;
      }
    }
    red[t] = best; __syncthreads();
    for (int s = 128; s > 0; s >>= 1) {
      if (t < s) red[t] = red[t] > red[t+s] ? red[t] : red[t+s];
      __syncthreads();
    }
    if (t == 0) {
      const int idx = NN - 1 - (int)(red[0] & 0xFFFFFFFFull);
      colmask[b * NN + idx] = 1.0f;
      vals[idx] = -1.0f;
    }
    __syncthreads();
  }
}

// ---------------------------------------------------------------------------
// inv_rs from bf16 attn (strided rows: 1024 payload, 2048 elem stride)
// ---------------------------------------------------------------------------
__global__ __launch_bounds__(256) void rs_kernel(const __bf16* __restrict__ attnb,
                                                 const float* __restrict__ colmask,
                                                 float* __restrict__ inv_rs)
{
  const int row = blockIdx.x;
  const int n = row & 1023;
  const int bh = row >> 10;
  const int b = bh >> 3;
  const int t = threadIdx.x;
  const int lane = t & 63, wv = t >> 6;
  const __bf16* ar = attnb + (size_t)row * 2048;
  const float* cm = colmask + b * NN;
  const int m = t << 2;
  const bf16x4 vb = *(const bf16x4*)(ar + m);
  const float4 c = *(const float4*)(cm + m);
  float acc = 0.f;
  acc += ((c.x != 0.f) || (m + 0 == n)) ? (float)vb.x : 0.f;
  acc += ((c.y != 0.f) || (m + 1 == n)) ? (float)vb.y : 0.f;
  acc += ((c.z != 0.f) || (m + 2 == n)) ? (float)vb.z : 0.f;
  acc += ((c.w != 0.f) || (m + 3 == n)) ? (float)vb.w : 0.f;
  acc = waveSum(acc);
  __shared__ float wred[4];
  if (lane == 0) wred[wv] = acc;
  __syncthreads();
  if (t == 0) inv_rs[row] = 1.0f / (wred[0] + wred[1] + wred[2] + wred[3] + 1e-16f);
}

// ---------------------------------------------------------------------------
// cs stage 1: partial[chunk][bh][m] = sum over n in chunk of e*ir[n]
// grid (8, B*H). Deterministic (fixed chunk order reduced in stage 2).
// ---------------------------------------------------------------------------
__global__ __launch_bounds__(256) void cs_part_kernel(const __bf16* __restrict__ attnb,
                                                      const float* __restrict__ colmask,
                                                      const float* __restrict__ inv_rs,
                                                      float* __restrict__ part)
{
  const int bh = blockIdx.y;
  const int b = bh >> 3;
  const int chunk = blockIdx.x;       // 0..7
  const int m0 = threadIdx.x << 2;
  const __bf16* ab = attnb + (size_t)bh * NN * 2048;
  const float* ir = inv_rs + bh * NN;
  const float4 cm = *(const float4*)(colmask + b * NN + m0);
  float a0 = 0.f, a1 = 0.f, a2 = 0.f, a3 = 0.f;
  const int n0 = chunk * 128, n1 = n0 + 128;
  for (int n = n0; n < n1; ++n) {
    const bf16x4 vb = *(const bf16x4*)(ab + (size_t)n * 2048 + m0);
    const float w = ir[n];
    a0 += ((cm.x != 0.f) || (m0 + 0 == n)) ? (float)vb.x * w : 0.f;
    a1 += ((cm.y != 0.f) || (m0 + 1 == n)) ? (float)vb.y * w : 0.f;
    a2 += ((cm.z != 0.f) || (m0 + 2 == n)) ? (float)vb.z * w : 0.f;
    a3 += ((cm.w != 0.f) || (m0 + 3 == n)) ? (float)vb.w * w : 0.f;
  }
  float4 o; o.x = a0; o.y = a1; o.z = a2; o.w = a3;
  *(float4*)(part + ((size_t)chunk * BB * HH + bh) * NN + m0) = o;
}

// ---------------------------------------------------------------------------
// cs stage 2: isc[bh][m] = rsqrt( sum_c part[c][bh][m] + 1e-16 )
// ---------------------------------------------------------------------------
__global__ __launch_bounds__(256) void cs_fin_kernel(const float* __restrict__ part,
                                                     float* __restrict__ isc)
{
  const int bh = blockIdx.x;
  const int m0 = threadIdx.x << 2;
  float a0 = 0.f, a1 = 0.f, a2 = 0.f, a3 = 0.f;
#pragma unroll
  for (int c = 0; c < 8; ++c) {
    const float4 p = *(const float4*)(part + ((size_t)c * BB * HH + bh) * NN + m0);
    a0 += p.x; a1 += p.y; a2 += p.z; a3 += p.w;
  }
  float4 o;
  o.x = 1.0f / sqrtf(a0 + 1e-16f);
  o.y = 1.0f / sqrtf(a1 + 1e-16f);
  o.z = 1.0f / sqrtf(a2 + 1e-16f);
  o.w = 1.0f / sqrtf(a3 + 1e-16f);
  *(float4*)(isc + (size_t)bh * NN + m0) = o;
}

// ---------------------------------------------------------------------------
// Gb[b,h,n,m] = bf16( e * inv_rs[n] * isc[m] ), e from bf16 attn.
// ---------------------------------------------------------------------------
__global__ __launch_bounds__(256) void g_kernel(const __bf16* __restrict__ attnb,
                                                const float* __restrict__ colmask,
                                                const float* __restrict__ inv_rs,
                                                const float* __restrict__ isc,
                                                __bf16* __restrict__ Gb)
{
  const size_t idx = ((size_t)blockIdx.x * 256 + threadIdx.x) << 2;
  const size_t row = idx >> 10;
  const int m = (int)(idx & 1023);
  const int n = (int)(row & 1023);
  const int bh = (int)(row >> 10);
  const int b = bh >> 3;
  const bf16x4 vb = *(const bf16x4*)(attnb + row * 2048 + m);
  const float4 c = *(const float4*)(colmask + b * NN + m);
  const float4 s = *(const float4*)(isc + bh * NN + m);
  const float ir = inv_rs[row];
  bf16x4 o;
  o.x = (__bf16)((((c.x != 0.f) || (m + 0 == n)) ? (float)vb.x : 0.f) * ir * s.x);
  o.y = (__bf16)((((c.y != 0.f) || (m + 1 == n)) ? (float)vb.y : 0.f) * ir * s.y);
  o.z = (__bf16)((((c.z != 0.f) || (m + 2 == n)) ? (float)vb.z : 0.f) * ir * s.z);
  o.w = (__bf16)((((c.w != 0.f) || (m + 3 == n)) ? (float)vb.w : 0.f) * ir * s.w);
  *(bf16x4*)(Gb + idx) = o;
}

// ---------------------------------------------------------------------------
// out[b,h] = Gb @ Gb^T (symmetric, upper-triangle tiles, mirrored writes).
// 1D grid, bh-resident XCD swizzle: f = (bh%8) + 8*((bh/8)*36 + tri)
// ---------------------------------------------------------------------------
__global__ __launch_bounds__(256) void ggt_mfma_kernel(const __bf16* __restrict__ Gball,
                                                       float* __restrict__ outall)
{
  const int f = blockIdx.x;
  const int xcd = f & 7;
  const int g = f >> 3;               // (bh/8)*36 + tri
  const int bh = xcd + 8 * (g / 36);
  int tt = g % 36;

  const __bf16* A = Gball + ((size_t)bh << 20);
  float* C = outall + ((size_t)bh << 20);

  int ti = 0;
#pragma unroll
  for (int r = 0; r < 8; ++r) {
    const int len = 8 - r;
    if (tt < len) { ti = r; break; }
    tt -= len;
  }
  const int tj = ti + tt;

  __shared__ __bf16 As[128 * 32];
  __shared__ __bf16 Bs[128 * 32];

  const int tid  = threadIdx.x;
  const int lane = tid & 63;
  const int wid  = tid >> 6;
  const int wr   = wid >> 1;
  const int wc   = wid & 1;
  const int bM   = ti * 128;
  const int bN   = tj * 128;

  const int srow = wid * 16 + (lane >> 2);
  const int scol = (lane & 3) * 8;
  const __bf16* gA = A + (size_t)(bM + srow) * NN + scol;
  const __bf16* gB = A + (size_t)(bN + srow) * NN + scol;
  char* lA = (char*)As + wid * 16 * 64;
  char* lB = (char*)Bs + wid * 16 * 64;

  f32x4 acc[4][4];
  const f32x4 z = {0.f, 0.f, 0.f, 0.f};
#pragma unroll
  for (int m = 0; m < 4; ++m)
#pragma unroll
    for (int n = 0; n < 4; ++n) acc[m][n] = z;

  for (int k0 = 0; k0 < NN; k0 += 32) {
    async16(gA + k0,           lA);
    async16(gA + k0 + 64 * NN, lA + 64 * 64);
    async16(gB + k0,           lB);
    async16(gB + k0 + 64 * NN, lB + 64 * 64);
    __syncthreads();

    bf16x8 a[4], b[4];
    const int fb = (lane & 15) * 64 + (lane >> 4) * 16;
#pragma unroll
    for (int m = 0; m < 4; ++m)
      a[m] = *(const bf16x8*)((const char*)As + (wr * 64 + m * 16) * 64 + fb);
#pragma unroll
    for (int n = 0; n < 4; ++n)
      b[n] = *(const bf16x8*)((const char*)Bs + (wc * 64 + n * 16) * 64 + fb);
#pragma unroll
    for (int m = 0; m < 4; ++m)
#pragma unroll
      for (int n = 0; n < 4; ++n)
        acc[m][n] = __builtin_amdgcn_mfma_f32_16x16x32_bf16(a[m], b[n], acc[m][n], 0, 0, 0);
    __syncthreads();
  }

  const int fr = lane & 15;
  const int fq = lane >> 4;
#pragma unroll
  for (int m = 0; m < 4; ++m) {
    const int row0 = bM + wr * 64 + m * 16 + fq * 4;
#pragma unroll
    for (int n = 0; n < 4; ++n) {
      const int col = bN + wc * 64 + n * 16 + fr;
#pragma unroll
      for (int r = 0; r < 4; ++r)
        C[(size_t)(row0 + r) * NN + col] = acc[m][n][r];
    }
  }
  if (ti != tj) {
#pragma unroll
    for (int m = 0; m < 4; ++m) {
      const int colT = bM + wr * 64 + m * 16 + fq * 4;
#pragma unroll
      for (int n = 0; n < 4; ++n) {
        const int rowT = bN + wc * 64 + n * 16 + fr;
        *(f32x4*)(C + (size_t)rowT * NN + colT) = acc[m][n];
      }
    }
  }
}

// ---------------------------------------------------------------------------
extern "C" void kernel_launch(void* const* d_in, const int* in_sizes, int n_in,
                              void* d_out, int out_size, void* d_ws, size_t ws_size,
                              hipStream_t stream)
{
  const float* x = (const float*)d_in[0];   // [B,N,C]
  const float* W = (const float*)d_in[1];   // [2*H*C, C]
  float* attn = (float*)d_out;
  __bf16* attnb = (__bf16*)d_out;
  char* ws = (char*)d_ws;

  __bf16* qk_hi = (__bf16*)(ws + ((size_t)0   << 20));   // 64 MiB
  __bf16* qk_lo = (__bf16*)(ws + ((size_t)64  << 20));   // 64 MiB
  __bf16* Gb    = (__bf16*)(ws + ((size_t)0   << 20));   // 128 MiB (reuses qk)
  __bf16* x_hi  = (__bf16*)(ws + ((size_t)128 << 20));
  __bf16* x_lo  = (__bf16*)(ws + ((size_t)132 << 20));
  __bf16* W_hi  = (__bf16*)(ws + ((size_t)136 << 20));
  __bf16* W_lo  = (__bf16*)(ws + ((size_t)138 << 20));
  float*  se    = (float*)(ws + ((size_t)144 << 20));    // 32 MiB
  float*  cmask = (float*)(ws + ((size_t)176 << 20));
  float*  irs   = (float*)(ws + ((size_t)177 << 20));
  float*  isc   = (float*)(ws + ((size_t)178 << 20));
  float*  csp   = (float*)(ws + ((size_t)180 << 20));    // 2 MiB partials

  // 0. split x and W into bf16 hi/lo
  hipLaunchKernelGGL(split_kernel, dim3((BB*NN*CC/4 + 255)/256), dim3(256), 0, stream,
                     x, x_hi, x_lo, BB*NN*CC/4);
  hipLaunchKernelGGL(split_kernel, dim3((OUTCH*CC/4 + 255)/256), dim3(256), 0, stream,
                     W, W_hi, W_lo, OUTCH*CC/4);

  // 1. qk = x @ W^T (split-bf16 MFMA)
  hipLaunchKernelGGL(xw_mfma_kernel, dim3(OUTCH/128, (BB*NN)/128, 1), dim3(256), 0, stream,
                     x_hi, x_lo, W_hi, W_lo, qk_hi, qk_lo);

  // 2. logits = scale * q @ k^T -> d_out (f32), bh-resident swizzle
  hipLaunchKernelGGL(qkt_mfma_kernel, dim3(64 * 64), dim3(256), 0, stream,
                     qk_hi, qk_lo, attn);

  // 3+4. softmax (bf16 out in place) + head-sum
  hipLaunchKernelGGL(softmax_se_kernel, dim3(BB*NN), dim3(256), 0, stream, attn, se);

  // 5. top-5 union -> column mask
  hipMemsetAsync(cmask, 0, (size_t)BB * NN * 4, stream);
  hipLaunchKernelGGL(topk_kernel, dim3(BB*NN), dim3(256), 0, stream, se, cmask);

  // 6. row sums
  hipLaunchKernelGGL(rs_kernel, dim3(BB*HH*NN), dim3(256), 0, stream, attnb, cmask, irs);

  // 7. column sums (two-stage parallel)
  hipLaunchKernelGGL(cs_part_kernel, dim3(8, BB*HH), dim3(256), 0, stream,
                     attnb, cmask, irs, csp);
  hipLaunchKernelGGL(cs_fin_kernel, dim3(BB*HH), dim3(256), 0, stream, csp, isc);

  // 8. Gb = bf16( e * inv_rs * isc )
  hipLaunchKernelGGL(g_kernel, dim3((BB*HH*NN*(long long)NN) / 4 / 256), dim3(256), 0, stream,
                     attnb, cmask, irs, isc, Gb);

  // 9. out = Gb @ Gb^T (symmetric MFMA, bh-resident swizzle) -> d_out f32
  hipLaunchKernelGGL(ggt_mfma_kernel, dim3(36 * 64), dim3(256), 0, stream,
                     Gb, attn);

  (void)in_sizes; (void)n_in; (void)out_size; (void)ws_size;
}

// Round 6
// 577.403 us; speedup vs baseline: 5.4934x; 1.0154x over previous
//
#include <hip/hip_runtime.h>
#include <hip/hip_bf16.h>
#include <cstdint>
#include <cstddef>

#define BB 8
#define HH 8
#define NN 1024
#define CC 256
#define OUTCH 4096   // 2*H*C

typedef __attribute__((ext_vector_type(8))) __bf16 bf16x8;
typedef __attribute__((ext_vector_type(4))) __bf16 bf16x4;
typedef __attribute__((ext_vector_type(4))) float f32x4;

// ---------------------------------------------------------------------------
// async global->LDS, 16B per lane, wave-uniform LDS base + lane*16
// ---------------------------------------------------------------------------
__device__ inline void async16(const void* g, void* l)
{
  __builtin_amdgcn_global_load_lds(
      reinterpret_cast<const __attribute__((address_space(1))) unsigned int*>(
          reinterpret_cast<uintptr_t>(g)),
      reinterpret_cast<__attribute__((address_space(3))) unsigned int*>(
          reinterpret_cast<uintptr_t>(l)),
      16, 0, 0);
}

__device__ inline float waveMax(float v) {
#pragma unroll
  for (int o = 32; o > 0; o >>= 1) v = fmaxf(v, __shfl_xor(v, o, 64));
  return v;
}
__device__ inline float waveSum(float v) {
#pragma unroll
  for (int o = 32; o > 0; o >>= 1) v += __shfl_xor(v, o, 64);
  return v;
}

// ---------------------------------------------------------------------------
// split f32 -> (hi, lo) bf16 planes
// ---------------------------------------------------------------------------
__global__ __launch_bounds__(256) void split_kernel(const float* __restrict__ in,
                                                    __bf16* __restrict__ hi,
                                                    __bf16* __restrict__ lo, int n4)
{
  const int i = blockIdx.x * 256 + threadIdx.x;
  if (i >= n4) return;
  const float4 v = ((const float4*)in)[i];
  bf16x4 h, l;
  h.x = (__bf16)v.x; l.x = (__bf16)(v.x - (float)h.x);
  h.y = (__bf16)v.y; l.y = (__bf16)(v.y - (float)h.y);
  h.z = (__bf16)v.z; l.z = (__bf16)(v.z - (float)h.z);
  h.w = (__bf16)v.w; l.w = (__bf16)(v.w - (float)h.w);
  ((bf16x4*)hi)[i] = h;
  ((bf16x4*)lo)[i] = l;
}

// ---------------------------------------------------------------------------
// Split-bf16 MFMA GEMM #1: qk = x @ W^T, written as hi/lo bf16 planes.
// ---------------------------------------------------------------------------
__global__ __launch_bounds__(256) void xw_mfma_kernel(
    const __bf16* __restrict__ Ah, const __bf16* __restrict__ Al,
    const __bf16* __restrict__ Bh, const __bf16* __restrict__ Bl,
    __bf16* __restrict__ Chi, __bf16* __restrict__ Clo)
{
  __shared__ __bf16 AsH[128 * 32], AsL[128 * 32], BsH[128 * 32], BsL[128 * 32];

  const int tid = threadIdx.x, lane = tid & 63, wid = tid >> 6;
  const int wr = wid >> 1, wc = wid & 1;
  const int bM = blockIdx.y * 128, bN = blockIdx.x * 128;

  const int srow = wid * 16 + (lane >> 2);
  const int scol = (lane & 3) * 8;
  const __bf16* gAh = Ah + (size_t)(bM + srow) * CC + scol;
  const __bf16* gAl = Al + (size_t)(bM + srow) * CC + scol;
  const __bf16* gBh = Bh + (size_t)(bN + srow) * CC + scol;
  const __bf16* gBl = Bl + (size_t)(bN + srow) * CC + scol;
  char* lAh = (char*)AsH + wid * 16 * 64;
  char* lAl = (char*)AsL + wid * 16 * 64;
  char* lBh = (char*)BsH + wid * 16 * 64;
  char* lBl = (char*)BsL + wid * 16 * 64;

  f32x4 acc[4][4];
  const f32x4 z = {0.f, 0.f, 0.f, 0.f};
#pragma unroll
  for (int m = 0; m < 4; ++m)
#pragma unroll
    for (int n = 0; n < 4; ++n) acc[m][n] = z;

  for (int k0 = 0; k0 < CC; k0 += 32) {
    async16(gAh + k0, lAh); async16(gAh + k0 + 64 * CC, lAh + 64 * 64);
    async16(gAl + k0, lAl); async16(gAl + k0 + 64 * CC, lAl + 64 * 64);
    async16(gBh + k0, lBh); async16(gBh + k0 + 64 * CC, lBh + 64 * 64);
    async16(gBl + k0, lBl); async16(gBl + k0 + 64 * CC, lBl + 64 * 64);
    __syncthreads();

    bf16x8 ah[4], al[4], bh_[4], bl_[4];
    const int fb = (lane & 15) * 64 + (lane >> 4) * 16;
#pragma unroll
    for (int m = 0; m < 4; ++m) {
      ah[m] = *(const bf16x8*)((const char*)AsH + (wr * 64 + m * 16) * 64 + fb);
      al[m] = *(const bf16x8*)((const char*)AsL + (wr * 64 + m * 16) * 64 + fb);
    }
#pragma unroll
    for (int n = 0; n < 4; ++n) {
      bh_[n] = *(const bf16x8*)((const char*)BsH + (wc * 64 + n * 16) * 64 + fb);
      bl_[n] = *(const bf16x8*)((const char*)BsL + (wc * 64 + n * 16) * 64 + fb);
    }
#pragma unroll
    for (int m = 0; m < 4; ++m)
#pragma unroll
      for (int n = 0; n < 4; ++n) {
        acc[m][n] = __builtin_amdgcn_mfma_f32_16x16x32_bf16(al[m], bh_[n], acc[m][n], 0, 0, 0);
        acc[m][n] = __builtin_amdgcn_mfma_f32_16x16x32_bf16(ah[m], bl_[n], acc[m][n], 0, 0, 0);
        acc[m][n] = __builtin_amdgcn_mfma_f32_16x16x32_bf16(ah[m], bh_[n], acc[m][n], 0, 0, 0);
      }
    __syncthreads();
  }

  const int fr = lane & 15;
  const int fq = lane >> 4;
#pragma unroll
  for (int m = 0; m < 4; ++m) {
    const int row0 = bM + wr * 64 + m * 16 + fq * 4;
#pragma unroll
    for (int n = 0; n < 4; ++n) {
      const int col = bN + wc * 64 + n * 16 + fr;
#pragma unroll
      for (int r = 0; r < 4; ++r) {
        const float v = acc[m][n][r];
        const __bf16 h = (__bf16)v;
        const __bf16 l = (__bf16)(v - (float)h);
        Chi[(size_t)(row0 + r) * OUTCH + col] = h;
        Clo[(size_t)(row0 + r) * OUTCH + col] = l;
      }
    }
  }
}

// ---------------------------------------------------------------------------
// Split-bf16 MFMA GEMM #2: logits[b,h] = (1/16) * q_bh @ k_bh^T  -> f32
// 1D grid, bh-resident XCD swizzle: f = (bh%8) + 8*((bh/8)*64 + tile)
// ---------------------------------------------------------------------------
__global__ __launch_bounds__(256) void qkt_mfma_kernel(
    const __bf16* __restrict__ Qh, const __bf16* __restrict__ Ql,
    float* __restrict__ outall)
{
  const int f = blockIdx.x;
  const int xcd = f & 7;
  const int g = f >> 3;            // (bh/8)*64 + tile
  const int bh = xcd + 8 * (g >> 6);
  const int tile = g & 63;
  const int b = bh >> 3, h = bh & 7;
  const size_t qoff = (size_t)b * NN * OUTCH + (size_t)h * CC;
  const size_t koff = qoff + 2048;
  float* C = outall + ((size_t)bh << 20);

  __shared__ __bf16 AsH[128 * 32], AsL[128 * 32], BsH[128 * 32], BsL[128 * 32];

  const int tid = threadIdx.x, lane = tid & 63, wid = tid >> 6;
  const int wr = wid >> 1, wc = wid & 1;
  const int bM = (tile >> 3) * 128, bN = (tile & 7) * 128;

  const int srow = wid * 16 + (lane >> 2);
  const int scol = (lane & 3) * 8;
  const __bf16* gAh = Qh + qoff + (size_t)(bM + srow) * OUTCH + scol;
  const __bf16* gAl = Ql + qoff + (size_t)(bM + srow) * OUTCH + scol;
  const __bf16* gBh = Qh + koff + (size_t)(bN + srow) * OUTCH + scol;
  const __bf16* gBl = Ql + koff + (size_t)(bN + srow) * OUTCH + scol;
  char* lAh = (char*)AsH + wid * 16 * 64;
  char* lAl = (char*)AsL + wid * 16 * 64;
  char* lBh = (char*)BsH + wid * 16 * 64;
  char* lBl = (char*)BsL + wid * 16 * 64;

  f32x4 acc[4][4];
  const f32x4 z = {0.f, 0.f, 0.f, 0.f};
#pragma unroll
  for (int m = 0; m < 4; ++m)
#pragma unroll
    for (int n = 0; n < 4; ++n) acc[m][n] = z;

  for (int k0 = 0; k0 < CC; k0 += 32) {
    async16(gAh + k0, lAh); async16(gAh + k0 + (size_t)64 * OUTCH, lAh + 64 * 64);
    async16(gAl + k0, lAl); async16(gAl + k0 + (size_t)64 * OUTCH, lAl + 64 * 64);
    async16(gBh + k0, lBh); async16(gBh + k0 + (size_t)64 * OUTCH, lBh + 64 * 64);
    async16(gBl + k0, lBl); async16(gBl + k0 + (size_t)64 * OUTCH, lBl + 64 * 64);
    __syncthreads();

    bf16x8 ah[4], al[4], bh_[4], bl_[4];
    const int fb = (lane & 15) * 64 + (lane >> 4) * 16;
#pragma unroll
    for (int m = 0; m < 4; ++m) {
      ah[m] = *(const bf16x8*)((const char*)AsH + (wr * 64 + m * 16) * 64 + fb);
      al[m] = *(const bf16x8*)((const char*)AsL + (wr * 64 + m * 16) * 64 + fb);
    }
#pragma unroll
    for (int n = 0; n < 4; ++n) {
      bh_[n] = *(const bf16x8*)((const char*)BsH + (wc * 64 + n * 16) * 64 + fb);
      bl_[n] = *(const bf16x8*)((const char*)BsL + (wc * 64 + n * 16) * 64 + fb);
    }
#pragma unroll
    for (int m = 0; m < 4; ++m)
#pragma unroll
      for (int n = 0; n < 4; ++n) {
        acc[m][n] = __builtin_amdgcn_mfma_f32_16x16x32_bf16(al[m], bh_[n], acc[m][n], 0, 0, 0);
        acc[m][n] = __builtin_amdgcn_mfma_f32_16x16x32_bf16(ah[m], bl_[n], acc[m][n], 0, 0, 0);
        acc[m][n] = __builtin_amdgcn_mfma_f32_16x16x32_bf16(ah[m], bh_[n], acc[m][n], 0, 0, 0);
      }
    __syncthreads();
  }

  const int fr = lane & 15;
  const int fq = lane >> 4;
#pragma unroll
  for (int m = 0; m < 4; ++m) {
    const int row0 = bM + wr * 64 + m * 16 + fq * 4;
#pragma unroll
    for (int n = 0; n < 4; ++n) {
      const int col = bN + wc * 64 + n * 16 + fr;
#pragma unroll
      for (int r = 0; r < 4; ++r)
        C[(size_t)(row0 + r) * NN + col] = acc[m][n][r] * 0.0625f;
    }
  }
}

// ---------------------------------------------------------------------------
// Fused softmax + head-sum. f32 logits (d_out) in, bf16 attn -> ws (contig),
// se from pre-rounding f32 values (top-k path bit-identical to f32 version).
// ---------------------------------------------------------------------------
__global__ __launch_bounds__(256) void softmax_se_kernel(const float* __restrict__ logits,
                                                         __bf16* __restrict__ attnb,
                                                         float* __restrict__ se)
{
  const int bn = blockIdx.x;
  const int b = bn >> 10;
  const int n = bn & 1023;
  const int t = threadIdx.x;
  const int lane = t & 63, wv = t >> 6;
  __shared__ float wred[4];
  float4 acc = make_float4(0.f, 0.f, 0.f, 0.f);

#pragma unroll 1
  for (int h = 0; h < HH; ++h) {
    const size_t rowbase = (((size_t)(b * HH + h) << 10) + n) << 10;
    const float* ar = logits + rowbase;
    __bf16* arb = attnb + rowbase;
    float4 x = *(const float4*)(ar + (t << 2));
    float mx = waveMax(fmaxf(fmaxf(x.x, x.y), fmaxf(x.z, x.w)));
    if (lane == 0) wred[wv] = mx;
    __syncthreads();
    const float M = fmaxf(fmaxf(wred[0], wred[1]), fmaxf(wred[2], wred[3]));
    __syncthreads();

    float e0 = expf(x.x - M), e1 = expf(x.y - M), e2 = expf(x.z - M), e3 = expf(x.w - M);
    float s = waveSum(e0 + e1 + e2 + e3);
    if (lane == 0) wred[wv] = s;
    __syncthreads();
    const float inv = 1.0f / (wred[0] + wred[1] + wred[2] + wred[3]);

    const float o0 = e0 * inv, o1 = e1 * inv, o2 = e2 * inv, o3 = e3 * inv;
    bf16x4 ob; ob.x = (__bf16)o0; ob.y = (__bf16)o1; ob.z = (__bf16)o2; ob.w = (__bf16)o3;
    *(bf16x4*)(arb + (t << 2)) = ob;
    acc.x += o0; acc.y += o1; acc.z += o2; acc.w += o3;
    __syncthreads();
  }
  *(float4*)(se + (size_t)bn * NN + (t << 2)) = acc;
}

// ---------------------------------------------------------------------------
// Top-5 per row of sum_edge; colmask[b, idx] = 1 for each winner.
// ---------------------------------------------------------------------------
__global__ __launch_bounds__(256) void topk_kernel(const float* __restrict__ se,
                                                   float* __restrict__ colmask)
{
  const int bn = blockIdx.x;
  const int b = bn >> 10;
  const int t = threadIdx.x;
  __shared__ float vals[NN];
  __shared__ unsigned long long red[256];
  const float* rowp = se + (size_t)bn * NN;
  for (int i = t; i < NN; i += 256) vals[i] = rowp[i];
  __syncthreads();

  for (int it = 0; it < 5; ++it) {
    unsigned long long best = 0ull;
    for (int i = t; i < NN; i += 256) {
      const float v = vals[i];
      if (v >= 0.f) {
        unsigned long long key =
            ((unsigned long long)__float_as_uint(v) << 32) | (unsigned)(NN - 1 - i);
        if (key > best) best = key;
      }
    }
    red[t] = best; __syncthreads();
    for (int s = 128; s > 0; s >>= 1) {
      if (t < s) red[t] = red[t] > red[t+s] ? red[t] : red[t+s];
      __syncthreads();
    }
    if (t == 0) {
      const int idx = NN - 1 - (int)(red[0] & 0xFFFFFFFFull);
      colmask[b * NN + idx] = 1.0f;
      vals[idx] = -1.0f;
    }
    __syncthreads();
  }
}

// ---------------------------------------------------------------------------
// Fused rs+cs stage 1. Grid (16, B*H); block handles 64 rows; wave per 16 rows.
// Per row: masked row-sum (wave butterfly), ir = 1/(sum+eps) -> irs; then
// column partials a[m] += e*ir. Wave partials combined via LDS at the end.
// ---------------------------------------------------------------------------
__global__ __launch_bounds__(256) void cs_rs_kernel(const __bf16* __restrict__ attnb,
                                                    const float* __restrict__ colmask,
                                                    float* __restrict__ inv_rs,
                                                    float* __restrict__ part)
{
  const int bh = blockIdx.y;
  const int b = bh >> 3;
  const int chunk = blockIdx.x;        // 0..15
  const int t = threadIdx.x, lane = t & 63, wv = t >> 6;
  const __bf16* ab = attnb + ((size_t)bh << 20);
  const float* cm = colmask + b * NN;
  const int c0 = lane * 16;            // this lane's 16 columns

  float cmv[16];
#pragma unroll
  for (int q = 0; q < 4; ++q) {
    const float4 c4 = *(const float4*)(cm + c0 + q * 4);
    cmv[q*4+0] = c4.x; cmv[q*4+1] = c4.y; cmv[q*4+2] = c4.z; cmv[q*4+3] = c4.w;
  }

  float a[16];
#pragma unroll
  for (int j = 0; j < 16; ++j) a[j] = 0.f;

  const int nbase = chunk * 64 + wv * 16;
#pragma unroll 1
  for (int r = 0; r < 16; ++r) {
    const int n = nbase + r;
    const __bf16* rowp = ab + ((size_t)n << 10) + c0;
    const bf16x8 v0 = *(const bf16x8*)(rowp);
    const bf16x8 v1 = *(const bf16x8*)(rowp + 8);
    float e[16];
    float rsum = 0.f;
#pragma unroll
    for (int j = 0; j < 8; ++j) {
      const float val = ((cmv[j] != 0.f) || (c0 + j == n)) ? (float)v0[j] : 0.f;
      e[j] = val; rsum += val;
    }
#pragma unroll
    for (int j = 0; j < 8; ++j) {
      const float val = ((cmv[8+j] != 0.f) || (c0 + 8 + j == n)) ? (float)v1[j] : 0.f;
      e[8+j] = val; rsum += val;
    }
    rsum = waveSum(rsum);
    const float ir = 1.0f / (rsum + 1e-16f);
    if (lane == 0) inv_rs[bh * NN + n] = ir;
#pragma unroll
    for (int j = 0; j < 16; ++j) a[j] += e[j] * ir;
  }

  __shared__ float l[4][NN];
#pragma unroll
  for (int j = 0; j < 16; ++j) l[wv][c0 + j] = a[j];
  __syncthreads();
  const int m0 = t << 2;
  float4 o;
  o.x = l[0][m0+0] + l[1][m0+0] + l[2][m0+0] + l[3][m0+0];
  o.y = l[0][m0+1] + l[1][m0+1] + l[2][m0+1] + l[3][m0+1];
  o.z = l[0][m0+2] + l[1][m0+2] + l[2][m0+2] + l[3][m0+2];
  o.w = l[0][m0+3] + l[1][m0+3] + l[2][m0+3] + l[3][m0+3];
  *(float4*)(part + (((size_t)chunk * (BB*HH) + bh) << 10) + m0) = o;
}

// ---------------------------------------------------------------------------
// cs stage 2: isc = rsqrt(sum_c part + eps); also sel0 = colmask ? isc : 0.
// ---------------------------------------------------------------------------
__global__ __launch_bounds__(256) void cs_fin_kernel(const float* __restrict__ part,
                                                     const float* __restrict__ colmask,
                                                     float* __restrict__ isc,
                                                     float* __restrict__ sel0)
{
  const int bh = blockIdx.x;
  const int b = bh >> 3;
  const int m0 = threadIdx.x << 2;
  float a0 = 0.f, a1 = 0.f, a2 = 0.f, a3 = 0.f;
#pragma unroll
  for (int c = 0; c < 16; ++c) {
    const float4 p = *(const float4*)(part + (((size_t)c * (BB*HH) + bh) << 10) + m0);
    a0 += p.x; a1 += p.y; a2 += p.z; a3 += p.w;
  }
  float4 o;
  o.x = 1.0f / sqrtf(a0 + 1e-16f);
  o.y = 1.0f / sqrtf(a1 + 1e-16f);
  o.z = 1.0f / sqrtf(a2 + 1e-16f);
  o.w = 1.0f / sqrtf(a3 + 1e-16f);
  *(float4*)(isc + ((size_t)bh << 10) + m0) = o;
  const float4 cm = *(const float4*)(colmask + b * NN + m0);
  float4 s;
  s.x = (cm.x != 0.f) ? o.x : 0.f;
  s.y = (cm.y != 0.f) ? o.y : 0.f;
  s.z = (cm.z != 0.f) ? o.z : 0.f;
  s.w = (cm.w != 0.f) ? o.w : 0.f;
  *(float4*)(sel0 + ((size_t)bh << 10) + m0) = s;
}

// ---------------------------------------------------------------------------
// out[b,h] = G @ G^T with G generated ON THE FLY from attnb/irs/isc/sel0:
//   G[n,k] = bf16( attn[n,k] * ir[n] * (n==k ? isc[k] : sel0[k]) )
// Symmetric: upper-triangle tiles, mirrored writes. bh-resident XCD swizzle.
// ---------------------------------------------------------------------------
__global__ __launch_bounds__(256) void ggt_mfma_kernel(const __bf16* __restrict__ attnb,
                                                       const float* __restrict__ irs,
                                                       const float* __restrict__ iscb,
                                                       const float* __restrict__ sel0b,
                                                       float* __restrict__ outall)
{
  const int f = blockIdx.x;
  const int xcd = f & 7;
  const int g = f >> 3;               // (bh/8)*36 + tri
  const int bh = xcd + 8 * (g / 36);
  int tt = g % 36;

  const __bf16* A = attnb + ((size_t)bh << 20);
  const float* ir = irs + bh * NN;
  const float* isc = iscb + ((size_t)bh << 10);
  const float* sel0 = sel0b + ((size_t)bh << 10);
  float* C = outall + ((size_t)bh << 20);

  int ti = 0;
#pragma unroll
  for (int r = 0; r < 8; ++r) {
    const int len = 8 - r;
    if (tt < len) { ti = r; break; }
    tt -= len;
  }
  const int tj = ti + tt;

  __shared__ __bf16 As[128 * 32];
  __shared__ __bf16 Bs[128 * 32];

  const int tid  = threadIdx.x;
  const int lane = tid & 63;
  const int wid  = tid >> 6;
  const int wr   = wid >> 1;
  const int wc   = wid & 1;
  const int bM   = ti * 128;
  const int bN   = tj * 128;

  const int srow = wid * 16 + (lane >> 2);
  const int scol = (lane & 3) * 8;

  const int rA0 = bM + srow, rA1 = bM + 64 + srow;
  const int rB0 = bN + srow, rB1 = bN + 64 + srow;
  const float irA0 = ir[rA0], irA1 = ir[rA1], irB0 = ir[rB0], irB1 = ir[rB1];

  f32x4 acc[4][4];
  const f32x4 z = {0.f, 0.f, 0.f, 0.f};
#pragma unroll
  for (int m = 0; m < 4; ++m)
#pragma unroll
    for (int n = 0; n < 4; ++n) acc[m][n] = z;

  for (int k0 = 0; k0 < NN; k0 += 32) {
    const int kc = k0 + scol;
    // per-k-step scale vectors (shared by the 4 staged fragments)
    const float4 i0 = *(const float4*)(isc + kc);
    const float4 i1 = *(const float4*)(isc + kc + 4);
    const float4 s0 = *(const float4*)(sel0 + kc);
    const float4 s1 = *(const float4*)(sel0 + kc + 4);
    const float iv[8] = {i0.x, i0.y, i0.z, i0.w, i1.x, i1.y, i1.z, i1.w};
    const float sv[8] = {s0.x, s0.y, s0.z, s0.w, s1.x, s1.y, s1.z, s1.w};

    const bf16x8 vA0 = *(const bf16x8*)(A + ((size_t)rA0 << 10) + kc);
    const bf16x8 vA1 = *(const bf16x8*)(A + ((size_t)rA1 << 10) + kc);
    const bf16x8 vB0 = *(const bf16x8*)(A + ((size_t)rB0 << 10) + kc);
    const bf16x8 vB1 = *(const bf16x8*)(A + ((size_t)rB1 << 10) + kc);

    bf16x8 gA0, gA1, gB0, gB1;
#pragma unroll
    for (int j = 0; j < 8; ++j) {
      const int k = kc + j;
      gA0[j] = (__bf16)((float)vA0[j] * irA0 * ((k == rA0) ? iv[j] : sv[j]));
      gA1[j] = (__bf16)((float)vA1[j] * irA1 * ((k == rA1) ? iv[j] : sv[j]));
      gB0[j] = (__bf16)((float)vB0[j] * irB0 * ((k == rB0) ? iv[j] : sv[j]));
      gB1[j] = (__bf16)((float)vB1[j] * irB1 * ((k == rB1) ? iv[j] : sv[j]));
    }
    *(bf16x8*)(&As[srow * 32 + scol])        = gA0;
    *(bf16x8*)(&As[(64 + srow) * 32 + scol]) = gA1;
    *(bf16x8*)(&Bs[srow * 32 + scol])        = gB0;
    *(bf16x8*)(&Bs[(64 + srow) * 32 + scol]) = gB1;
    __syncthreads();

    bf16x8 a[4], b[4];
    const int fb = (lane & 15) * 64 + (lane >> 4) * 16;
#pragma unroll
    for (int m = 0; m < 4; ++m)
      a[m] = *(const bf16x8*)((const char*)As + (wr * 64 + m * 16) * 64 + fb);
#pragma unroll
    for (int n = 0; n < 4; ++n)
      b[n] = *(const bf16x8*)((const char*)Bs + (wc * 64 + n * 16) * 64 + fb);
#pragma unroll
    for (int m = 0; m < 4; ++m)
#pragma unroll
      for (int n = 0; n < 4; ++n)
        acc[m][n] = __builtin_amdgcn_mfma_f32_16x16x32_bf16(a[m], b[n], acc[m][n], 0, 0, 0);
    __syncthreads();
  }

  const int fr = lane & 15;
  const int fq = lane >> 4;
#pragma unroll
  for (int m = 0; m < 4; ++m) {
    const int row0 = bM + wr * 64 + m * 16 + fq * 4;
#pragma unroll
    for (int n = 0; n < 4; ++n) {
      const int col = bN + wc * 64 + n * 16 + fr;
#pragma unroll
      for (int r = 0; r < 4; ++r)
        C[(size_t)(row0 + r) * NN + col] = acc[m][n][r];
    }
  }
  if (ti != tj) {
#pragma unroll
    for (int m = 0; m < 4; ++m) {
      const int colT = bM + wr * 64 + m * 16 + fq * 4;
#pragma unroll
      for (int n = 0; n < 4; ++n) {
        const int rowT = bN + wc * 64 + n * 16 + fr;
        *(f32x4*)(C + (size_t)rowT * NN + colT) = acc[m][n];
      }
    }
  }
}

// ---------------------------------------------------------------------------
extern "C" void kernel_launch(void* const* d_in, const int* in_sizes, int n_in,
                              void* d_out, int out_size, void* d_ws, size_t ws_size,
                              hipStream_t stream)
{
  const float* x = (const float*)d_in[0];   // [B,N,C]
  const float* W = (const float*)d_in[1];   // [2*H*C, C]
  float* logits = (float*)d_out;            // f32 logits, later final out
  char* ws = (char*)d_ws;

  __bf16* qk_hi = (__bf16*)(ws + ((size_t)0   << 20));   // 64 MiB
  __bf16* qk_lo = (__bf16*)(ws + ((size_t)64  << 20));   // 64 MiB
  __bf16* attnb = (__bf16*)(ws + ((size_t)0   << 20));   // 128 MiB (reuses qk)
  __bf16* x_hi  = (__bf16*)(ws + ((size_t)128 << 20));
  __bf16* x_lo  = (__bf16*)(ws + ((size_t)132 << 20));
  __bf16* W_hi  = (__bf16*)(ws + ((size_t)136 << 20));
  __bf16* W_lo  = (__bf16*)(ws + ((size_t)138 << 20));
  float*  se    = (float*)(ws + ((size_t)144 << 20));    // 32 MiB
  float*  cmask = (float*)(ws + ((size_t)176 << 20));    // 32 KiB
  float*  irs   = (float*)(ws + ((size_t)177 << 20));    // 256 KiB
  float*  isc   = (float*)(ws + ((size_t)178 << 20));    // 256 KiB
  float*  sel0  = (float*)(ws + ((size_t)179 << 20));    // 256 KiB
  float*  csp   = (float*)(ws + ((size_t)180 << 20));    // 4 MiB partials

  // 0. split x and W into bf16 hi/lo
  hipLaunchKernelGGL(split_kernel, dim3((BB*NN*CC/4 + 255)/256), dim3(256), 0, stream,
                     x, x_hi, x_lo, BB*NN*CC/4);
  hipLaunchKernelGGL(split_kernel, dim3((OUTCH*CC/4 + 255)/256), dim3(256), 0, stream,
                     W, W_hi, W_lo, OUTCH*CC/4);

  // 1. qk = x @ W^T (split-bf16 MFMA)
  hipLaunchKernelGGL(xw_mfma_kernel, dim3(OUTCH/128, (BB*NN)/128, 1), dim3(256), 0, stream,
                     x_hi, x_lo, W_hi, W_lo, qk_hi, qk_lo);

  // 2. logits = scale * q @ k^T -> d_out (f32), bh-resident swizzle
  hipLaunchKernelGGL(qkt_mfma_kernel, dim3(64 * 64), dim3(256), 0, stream,
                     qk_hi, qk_lo, logits);

  // 3+4. softmax (f32 logits -> bf16 attn in ws) + head-sum
  hipLaunchKernelGGL(softmax_se_kernel, dim3(BB*NN), dim3(256), 0, stream,
                     logits, attnb, se);

  // 5. top-5 union -> column mask
  hipMemsetAsync(cmask, 0, (size_t)BB * NN * 4, stream);
  hipLaunchKernelGGL(topk_kernel, dim3(BB*NN), dim3(256), 0, stream, se, cmask);

  // 6+7. fused row sums + column partials, then finalize isc/sel0
  hipLaunchKernelGGL(cs_rs_kernel, dim3(16, BB*HH), dim3(256), 0, stream,
                     attnb, cmask, irs, csp);
  hipLaunchKernelGGL(cs_fin_kernel, dim3(BB*HH), dim3(256), 0, stream,
                     csp, cmask, isc, sel0);

  // 8+9. out = G @ G^T with on-the-fly G (symmetric, swizzled) -> d_out f32
  hipLaunchKernelGGL(ggt_mfma_kernel, dim3(36 * 64), dim3(256), 0, stream,
                     attnb, irs, isc, sel0, logits);

  (void)in_sizes; (void)n_in; (void)out_size; (void)ws_size;
}

// Round 7
// 561.319 us; speedup vs baseline: 5.6508x; 1.0287x over previous
//
#include <hip/hip_runtime.h>
#include <hip/hip_bf16.h>
#include <cstdint>
#include <cstddef>

#define BB 8
#define HH 8
#define NN 1024
#define CC 256
#define OUTCH 4096   // 2*H*C

typedef __attribute__((ext_vector_type(8))) __bf16 bf16x8;
typedef __attribute__((ext_vector_type(4))) __bf16 bf16x4;
typedef __attribute__((ext_vector_type(4))) float f32x4;

// ---------------------------------------------------------------------------
// async global->LDS, 16B per lane, wave-uniform LDS base + lane*16
// ---------------------------------------------------------------------------
__device__ inline void async16(const void* g, void* l)
{
  __builtin_amdgcn_global_load_lds(
      reinterpret_cast<const __attribute__((address_space(1))) unsigned int*>(
          reinterpret_cast<uintptr_t>(g)),
      reinterpret_cast<__attribute__((address_space(3))) unsigned int*>(
          reinterpret_cast<uintptr_t>(l)),
      16, 0, 0);
}

__device__ inline float waveMax(float v) {
#pragma unroll
  for (int o = 32; o > 0; o >>= 1) v = fmaxf(v, __shfl_xor(v, o, 64));
  return v;
}
__device__ inline float waveSum(float v) {
#pragma unroll
  for (int o = 32; o > 0; o >>= 1) v += __shfl_xor(v, o, 64);
  return v;
}

// ---------------------------------------------------------------------------
// split f32 -> (hi, lo) bf16 planes
// ---------------------------------------------------------------------------
__global__ __launch_bounds__(256) void split_kernel(const float* __restrict__ in,
                                                    __bf16* __restrict__ hi,
                                                    __bf16* __restrict__ lo, int n4)
{
  const int i = blockIdx.x * 256 + threadIdx.x;
  if (i >= n4) return;
  const float4 v = ((const float4*)in)[i];
  bf16x4 h, l;
  h.x = (__bf16)v.x; l.x = (__bf16)(v.x - (float)h.x);
  h.y = (__bf16)v.y; l.y = (__bf16)(v.y - (float)h.y);
  h.z = (__bf16)v.z; l.z = (__bf16)(v.z - (float)h.z);
  h.w = (__bf16)v.w; l.w = (__bf16)(v.w - (float)h.w);
  ((bf16x4*)hi)[i] = h;
  ((bf16x4*)lo)[i] = l;
}

// ---------------------------------------------------------------------------
// Split-bf16 MFMA GEMM #1: qk = x @ W^T, written as hi/lo bf16 planes.
// ---------------------------------------------------------------------------
__global__ __launch_bounds__(256) void xw_mfma_kernel(
    const __bf16* __restrict__ Ah, const __bf16* __restrict__ Al,
    const __bf16* __restrict__ Bh, const __bf16* __restrict__ Bl,
    __bf16* __restrict__ Chi, __bf16* __restrict__ Clo)
{
  __shared__ __bf16 AsH[128 * 32], AsL[128 * 32], BsH[128 * 32], BsL[128 * 32];

  const int tid = threadIdx.x, lane = tid & 63, wid = tid >> 6;
  const int wr = wid >> 1, wc = wid & 1;
  const int bM = blockIdx.y * 128, bN = blockIdx.x * 128;

  const int srow = wid * 16 + (lane >> 2);
  const int scol = (lane & 3) * 8;
  const __bf16* gAh = Ah + (size_t)(bM + srow) * CC + scol;
  const __bf16* gAl = Al + (size_t)(bM + srow) * CC + scol;
  const __bf16* gBh = Bh + (size_t)(bN + srow) * CC + scol;
  const __bf16* gBl = Bl + (size_t)(bN + srow) * CC + scol;
  char* lAh = (char*)AsH + wid * 16 * 64;
  char* lAl = (char*)AsL + wid * 16 * 64;
  char* lBh = (char*)BsH + wid * 16 * 64;
  char* lBl = (char*)BsL + wid * 16 * 64;

  f32x4 acc[4][4];
  const f32x4 z = {0.f, 0.f, 0.f, 0.f};
#pragma unroll
  for (int m = 0; m < 4; ++m)
#pragma unroll
    for (int n = 0; n < 4; ++n) acc[m][n] = z;

  for (int k0 = 0; k0 < CC; k0 += 32) {
    async16(gAh + k0, lAh); async16(gAh + k0 + 64 * CC, lAh + 64 * 64);
    async16(gAl + k0, lAl); async16(gAl + k0 + 64 * CC, lAl + 64 * 64);
    async16(gBh + k0, lBh); async16(gBh + k0 + 64 * CC, lBh + 64 * 64);
    async16(gBl + k0, lBl); async16(gBl + k0 + 64 * CC, lBl + 64 * 64);
    __syncthreads();

    bf16x8 ah[4], al[4], bh_[4], bl_[4];
    const int fb = (lane & 15) * 64 + (lane >> 4) * 16;
#pragma unroll
    for (int m = 0; m < 4; ++m) {
      ah[m] = *(const bf16x8*)((const char*)AsH + (wr * 64 + m * 16) * 64 + fb);
      al[m] = *(const bf16x8*)((const char*)AsL + (wr * 64 + m * 16) * 64 + fb);
    }
#pragma unroll
    for (int n = 0; n < 4; ++n) {
      bh_[n] = *(const bf16x8*)((const char*)BsH + (wc * 64 + n * 16) * 64 + fb);
      bl_[n] = *(const bf16x8*)((const char*)BsL + (wc * 64 + n * 16) * 64 + fb);
    }
#pragma unroll
    for (int m = 0; m < 4; ++m)
#pragma unroll
      for (int n = 0; n < 4; ++n) {
        acc[m][n] = __builtin_amdgcn_mfma_f32_16x16x32_bf16(al[m], bh_[n], acc[m][n], 0, 0, 0);
        acc[m][n] = __builtin_amdgcn_mfma_f32_16x16x32_bf16(ah[m], bl_[n], acc[m][n], 0, 0, 0);
        acc[m][n] = __builtin_amdgcn_mfma_f32_16x16x32_bf16(ah[m], bh_[n], acc[m][n], 0, 0, 0);
      }
    __syncthreads();
  }

  const int fr = lane & 15;
  const int fq = lane >> 4;
#pragma unroll
  for (int m = 0; m < 4; ++m) {
    const int row0 = bM + wr * 64 + m * 16 + fq * 4;
#pragma unroll
    for (int n = 0; n < 4; ++n) {
      const int col = bN + wc * 64 + n * 16 + fr;
#pragma unroll
      for (int r = 0; r < 4; ++r) {
        const float v = acc[m][n][r];
        const __bf16 h = (__bf16)v;
        const __bf16 l = (__bf16)(v - (float)h);
        Chi[(size_t)(row0 + r) * OUTCH + col] = h;
        Clo[(size_t)(row0 + r) * OUTCH + col] = l;
      }
    }
  }
}

// ---------------------------------------------------------------------------
// Split-bf16 MFMA GEMM #2: logits[b,h] = (1/16) * q_bh @ k_bh^T  -> f32
// 1D grid, bh-resident XCD swizzle: f = (bh%8) + 8*((bh/8)*64 + tile)
// ---------------------------------------------------------------------------
__global__ __launch_bounds__(256) void qkt_mfma_kernel(
    const __bf16* __restrict__ Qh, const __bf16* __restrict__ Ql,
    float* __restrict__ outall)
{
  const int f = blockIdx.x;
  const int xcd = f & 7;
  const int g = f >> 3;            // (bh/8)*64 + tile
  const int bh = xcd + 8 * (g >> 6);
  const int tile = g & 63;
  const int b = bh >> 3, h = bh & 7;
  const size_t qoff = (size_t)b * NN * OUTCH + (size_t)h * CC;
  const size_t koff = qoff + 2048;
  float* C = outall + ((size_t)bh << 20);

  __shared__ __bf16 AsH[128 * 32], AsL[128 * 32], BsH[128 * 32], BsL[128 * 32];

  const int tid = threadIdx.x, lane = tid & 63, wid = tid >> 6;
  const int wr = wid >> 1, wc = wid & 1;
  const int bM = (tile >> 3) * 128, bN = (tile & 7) * 128;

  const int srow = wid * 16 + (lane >> 2);
  const int scol = (lane & 3) * 8;
  const __bf16* gAh = Qh + qoff + (size_t)(bM + srow) * OUTCH + scol;
  const __bf16* gAl = Ql + qoff + (size_t)(bM + srow) * OUTCH + scol;
  const __bf16* gBh = Qh + koff + (size_t)(bN + srow) * OUTCH + scol;
  const __bf16* gBl = Ql + koff + (size_t)(bN + srow) * OUTCH + scol;
  char* lAh = (char*)AsH + wid * 16 * 64;
  char* lAl = (char*)AsL + wid * 16 * 64;
  char* lBh = (char*)BsH + wid * 16 * 64;
  char* lBl = (char*)BsL + wid * 16 * 64;

  f32x4 acc[4][4];
  const f32x4 z = {0.f, 0.f, 0.f, 0.f};
#pragma unroll
  for (int m = 0; m < 4; ++m)
#pragma unroll
    for (int n = 0; n < 4; ++n) acc[m][n] = z;

  for (int k0 = 0; k0 < CC; k0 += 32) {
    async16(gAh + k0, lAh); async16(gAh + k0 + (size_t)64 * OUTCH, lAh + 64 * 64);
    async16(gAl + k0, lAl); async16(gAl + k0 + (size_t)64 * OUTCH, lAl + 64 * 64);
    async16(gBh + k0, lBh); async16(gBh + k0 + (size_t)64 * OUTCH, lBh + 64 * 64);
    async16(gBl + k0, lBl); async16(gBl + k0 + (size_t)64 * OUTCH, lBl + 64 * 64);
    __syncthreads();

    bf16x8 ah[4], al[4], bh_[4], bl_[4];
    const int fb = (lane & 15) * 64 + (lane >> 4) * 16;
#pragma unroll
    for (int m = 0; m < 4; ++m) {
      ah[m] = *(const bf16x8*)((const char*)AsH + (wr * 64 + m * 16) * 64 + fb);
      al[m] = *(const bf16x8*)((const char*)AsL + (wr * 64 + m * 16) * 64 + fb);
    }
#pragma unroll
    for (int n = 0; n < 4; ++n) {
      bh_[n] = *(const bf16x8*)((const char*)BsH + (wc * 64 + n * 16) * 64 + fb);
      bl_[n] = *(const bf16x8*)((const char*)BsL + (wc * 64 + n * 16) * 64 + fb);
    }
#pragma unroll
    for (int m = 0; m < 4; ++m)
#pragma unroll
      for (int n = 0; n < 4; ++n) {
        acc[m][n] = __builtin_amdgcn_mfma_f32_16x16x32_bf16(al[m], bh_[n], acc[m][n], 0, 0, 0);
        acc[m][n] = __builtin_amdgcn_mfma_f32_16x16x32_bf16(ah[m], bl_[n], acc[m][n], 0, 0, 0);
        acc[m][n] = __builtin_amdgcn_mfma_f32_16x16x32_bf16(ah[m], bh_[n], acc[m][n], 0, 0, 0);
      }
    __syncthreads();
  }

  const int fr = lane & 15;
  const int fq = lane >> 4;
#pragma unroll
  for (int m = 0; m < 4; ++m) {
    const int row0 = bM + wr * 64 + m * 16 + fq * 4;
#pragma unroll
    for (int n = 0; n < 4; ++n) {
      const int col = bN + wc * 64 + n * 16 + fr;
#pragma unroll
      for (int r = 0; r < 4; ++r)
        C[(size_t)(row0 + r) * NN + col] = acc[m][n][r] * 0.0625f;
    }
  }
}

// ---------------------------------------------------------------------------
// Fused softmax + head-sum. f32 logits (d_out) in, bf16 attn -> ws (contig),
// se from pre-rounding f32 values (top-k path bit-identical to f32 version).
// ---------------------------------------------------------------------------
__global__ __launch_bounds__(256) void softmax_se_kernel(const float* __restrict__ logits,
                                                         __bf16* __restrict__ attnb,
                                                         float* __restrict__ se)
{
  const int bn = blockIdx.x;
  const int b = bn >> 10;
  const int n = bn & 1023;
  const int t = threadIdx.x;
  const int lane = t & 63, wv = t >> 6;
  __shared__ float wred[4];
  float4 acc = make_float4(0.f, 0.f, 0.f, 0.f);

#pragma unroll 1
  for (int h = 0; h < HH; ++h) {
    const size_t rowbase = (((size_t)(b * HH + h) << 10) + n) << 10;
    const float* ar = logits + rowbase;
    __bf16* arb = attnb + rowbase;
    float4 x = *(const float4*)(ar + (t << 2));
    float mx = waveMax(fmaxf(fmaxf(x.x, x.y), fmaxf(x.z, x.w)));
    if (lane == 0) wred[wv] = mx;
    __syncthreads();
    const float M = fmaxf(fmaxf(wred[0], wred[1]), fmaxf(wred[2], wred[3]));
    __syncthreads();

    float e0 = expf(x.x - M), e1 = expf(x.y - M), e2 = expf(x.z - M), e3 = expf(x.w - M);
    float s = waveSum(e0 + e1 + e2 + e3);
    if (lane == 0) wred[wv] = s;
    __syncthreads();
    const float inv = 1.0f / (wred[0] + wred[1] + wred[2] + wred[3]);

    const float o0 = e0 * inv, o1 = e1 * inv, o2 = e2 * inv, o3 = e3 * inv;
    bf16x4 ob; ob.x = (__bf16)o0; ob.y = (__bf16)o1; ob.z = (__bf16)o2; ob.w = (__bf16)o3;
    *(bf16x4*)(arb + (t << 2)) = ob;
    acc.x += o0; acc.y += o1; acc.z += o2; acc.w += o3;
    __syncthreads();
  }
  *(float4*)(se + (size_t)bn * NN + (t << 2)) = acc;
}

// ---------------------------------------------------------------------------
// Top-5 per row of sum_edge; colmask[b, idx] = 1 for each winner.
// ---------------------------------------------------------------------------
__global__ __launch_bounds__(256) void topk_kernel(const float* __restrict__ se,
                                                   float* __restrict__ colmask)
{
  const int bn = blockIdx.x;
  const int b = bn >> 10;
  const int t = threadIdx.x;
  __shared__ float vals[NN];
  __shared__ unsigned long long red[256];
  const float* rowp = se + (size_t)bn * NN;
  for (int i = t; i < NN; i += 256) vals[i] = rowp[i];
  __syncthreads();

  for (int it = 0; it < 5; ++it) {
    unsigned long long best = 0ull;
    for (int i = t; i < NN; i += 256) {
      const float v = vals[i];
      if (v >= 0.f) {
        unsigned long long key =
            ((unsigned long long)__float_as_uint(v) << 32) | (unsigned)(NN - 1 - i);
        if (key > best) best = key;
      }
    }
    red[t] = best; __syncthreads();
    for (int s = 128; s > 0; s >>= 1) {
      if (t < s) red[t] = red[t] > red[t+s] ? red[t] : red[t+s];
      __syncthreads();
    }
    if (t == 0) {
      const int idx = NN - 1 - (int)(red[0] & 0xFFFFFFFFull);
      colmask[b * NN + idx] = 1.0f;
      vals[idx] = -1.0f;
    }
    __syncthreads();
  }
}

// ---------------------------------------------------------------------------
// Fused rs+cs stage 1. Grid (16, B*H); block handles 64 rows; wave per 16 rows.
// ---------------------------------------------------------------------------
__global__ __launch_bounds__(256) void cs_rs_kernel(const __bf16* __restrict__ attnb,
                                                    const float* __restrict__ colmask,
                                                    float* __restrict__ inv_rs,
                                                    float* __restrict__ part)
{
  const int bh = blockIdx.y;
  const int b = bh >> 3;
  const int chunk = blockIdx.x;        // 0..15
  const int t = threadIdx.x, lane = t & 63, wv = t >> 6;
  const __bf16* ab = attnb + ((size_t)bh << 20);
  const float* cm = colmask + b * NN;
  const int c0 = lane * 16;            // this lane's 16 columns

  float cmv[16];
#pragma unroll
  for (int q = 0; q < 4; ++q) {
    const float4 c4 = *(const float4*)(cm + c0 + q * 4);
    cmv[q*4+0] = c4.x; cmv[q*4+1] = c4.y; cmv[q*4+2] = c4.z; cmv[q*4+3] = c4.w;
  }

  float a[16];
#pragma unroll
  for (int j = 0; j < 16; ++j) a[j] = 0.f;

  const int nbase = chunk * 64 + wv * 16;
#pragma unroll 1
  for (int r = 0; r < 16; ++r) {
    const int n = nbase + r;
    const __bf16* rowp = ab + ((size_t)n << 10) + c0;
    const bf16x8 v0 = *(const bf16x8*)(rowp);
    const bf16x8 v1 = *(const bf16x8*)(rowp + 8);
    float e[16];
    float rsum = 0.f;
#pragma unroll
    for (int j = 0; j < 8; ++j) {
      const float val = ((cmv[j] != 0.f) || (c0 + j == n)) ? (float)v0[j] : 0.f;
      e[j] = val; rsum += val;
    }
#pragma unroll
    for (int j = 0; j < 8; ++j) {
      const float val = ((cmv[8+j] != 0.f) || (c0 + 8 + j == n)) ? (float)v1[j] : 0.f;
      e[8+j] = val; rsum += val;
    }
    rsum = waveSum(rsum);
    const float ir = 1.0f / (rsum + 1e-16f);
    if (lane == 0) inv_rs[bh * NN + n] = ir;
#pragma unroll
    for (int j = 0; j < 16; ++j) a[j] += e[j] * ir;
  }

  __shared__ float l[4][NN];
#pragma unroll
  for (int j = 0; j < 16; ++j) l[wv][c0 + j] = a[j];
  __syncthreads();
  const int m0 = t << 2;
  float4 o;
  o.x = l[0][m0+0] + l[1][m0+0] + l[2][m0+0] + l[3][m0+0];
  o.y = l[0][m0+1] + l[1][m0+1] + l[2][m0+1] + l[3][m0+1];
  o.z = l[0][m0+2] + l[1][m0+2] + l[2][m0+2] + l[3][m0+2];
  o.w = l[0][m0+3] + l[1][m0+3] + l[2][m0+3] + l[3][m0+3];
  *(float4*)(part + (((size_t)chunk * (BB*HH) + bh) << 10) + m0) = o;
}

// ---------------------------------------------------------------------------
// cs stage 2: isc = rsqrt(sum_c part + eps)
// ---------------------------------------------------------------------------
__global__ __launch_bounds__(256) void cs_fin_kernel(const float* __restrict__ part,
                                                     float* __restrict__ isc)
{
  const int bh = blockIdx.x;
  const int m0 = threadIdx.x << 2;
  float a0 = 0.f, a1 = 0.f, a2 = 0.f, a3 = 0.f;
#pragma unroll
  for (int c = 0; c < 16; ++c) {
    const float4 p = *(const float4*)(part + (((size_t)c * (BB*HH) + bh) << 10) + m0);
    a0 += p.x; a1 += p.y; a2 += p.z; a3 += p.w;
  }
  float4 o;
  o.x = 1.0f / sqrtf(a0 + 1e-16f);
  o.y = 1.0f / sqrtf(a1 + 1e-16f);
  o.z = 1.0f / sqrtf(a2 + 1e-16f);
  o.w = 1.0f / sqrtf(a3 + 1e-16f);
  *(float4*)(isc + ((size_t)bh << 10) + m0) = o;
}

// ---------------------------------------------------------------------------
// Gb[b,h,n,m] = bf16( e * inv_rs[n] * isc[m] ), e from contiguous bf16 attn.
// ---------------------------------------------------------------------------
__global__ __launch_bounds__(256) void g_kernel(const __bf16* __restrict__ attnb,
                                                const float* __restrict__ colmask,
                                                const float* __restrict__ inv_rs,
                                                const float* __restrict__ isc,
                                                __bf16* __restrict__ Gb)
{
  const size_t idx = ((size_t)blockIdx.x * 256 + threadIdx.x) << 2;
  const size_t row = idx >> 10;
  const int m = (int)(idx & 1023);
  const int n = (int)(row & 1023);
  const int bh = (int)(row >> 10);
  const int b = bh >> 3;
  const bf16x4 vb = *(const bf16x4*)(attnb + idx);
  const float4 c = *(const float4*)(colmask + b * NN + m);
  const float4 s = *(const float4*)(isc + ((size_t)bh << 10) + m);
  const float ir = inv_rs[row];
  bf16x4 o;
  o.x = (__bf16)((((c.x != 0.f) || (m + 0 == n)) ? (float)vb.x : 0.f) * ir * s.x);
  o.y = (__bf16)((((c.y != 0.f) || (m + 1 == n)) ? (float)vb.y : 0.f) * ir * s.y);
  o.z = (__bf16)((((c.z != 0.f) || (m + 2 == n)) ? (float)vb.z : 0.f) * ir * s.z);
  o.w = (__bf16)((((c.w != 0.f) || (m + 3 == n)) ? (float)vb.w : 0.f) * ir * s.w);
  *(bf16x4*)(Gb + idx) = o;
}

// ---------------------------------------------------------------------------
// out[b,h] = Gb @ Gb^T (symmetric, upper-triangle tiles, mirrored writes).
// 1D grid, bh-resident XCD swizzle: f = (bh%8) + 8*((bh/8)*36 + tri)
// ---------------------------------------------------------------------------
__global__ __launch_bounds__(256) void ggt_mfma_kernel(const __bf16* __restrict__ Gball,
                                                       float* __restrict__ outall)
{
  const int f = blockIdx.x;
  const int xcd = f & 7;
  const int g = f >> 3;               // (bh/8)*36 + tri
  const int bh = xcd + 8 * (g / 36);
  int tt = g % 36;

  const __bf16* A = Gball + ((size_t)bh << 20);
  float* C = outall + ((size_t)bh << 20);

  int ti = 0;
#pragma unroll
  for (int r = 0; r < 8; ++r) {
    const int len = 8 - r;
    if (tt < len) { ti = r; break; }
    tt -= len;
  }
  const int tj = ti + tt;

  __shared__ __bf16 As[128 * 32];
  __shared__ __bf16 Bs[128 * 32];

  const int tid  = threadIdx.x;
  const int lane = tid & 63;
  const int wid  = tid >> 6;
  const int wr   = wid >> 1;
  const int wc   = wid & 1;
  const int bM   = ti * 128;
  const int bN   = tj * 128;

  const int srow = wid * 16 + (lane >> 2);
  const int scol = (lane & 3) * 8;
  const __bf16* gA = A + (size_t)(bM + srow) * NN + scol;
  const __bf16* gB = A + (size_t)(bN + srow) * NN + scol;
  char* lA = (char*)As + wid * 16 * 64;
  char* lB = (char*)Bs + wid * 16 * 64;

  f32x4 acc[4][4];
  const f32x4 z = {0.f, 0.f, 0.f, 0.f};
#pragma unroll
  for (int m = 0; m < 4; ++m)
#pragma unroll
    for (int n = 0; n < 4; ++n) acc[m][n] = z;

  for (int k0 = 0; k0 < NN; k0 += 32) {
    async16(gA + k0,           lA);
    async16(gA + k0 + 64 * NN, lA + 64 * 64);
    async16(gB + k0,           lB);
    async16(gB + k0 + 64 * NN, lB + 64 * 64);
    __syncthreads();

    bf16x8 a[4], b[4];
    const int fb = (lane & 15) * 64 + (lane >> 4) * 16;
#pragma unroll
    for (int m = 0; m < 4; ++m)
      a[m] = *(const bf16x8*)((const char*)As + (wr * 64 + m * 16) * 64 + fb);
#pragma unroll
    for (int n = 0; n < 4; ++n)
      b[n] = *(const bf16x8*)((const char*)Bs + (wc * 64 + n * 16) * 64 + fb);
#pragma unroll
    for (int m = 0; m < 4; ++m)
#pragma unroll
      for (int n = 0; n < 4; ++n)
        acc[m][n] = __builtin_amdgcn_mfma_f32_16x16x32_bf16(a[m], b[n], acc[m][n], 0, 0, 0);
    __syncthreads();
  }

  const int fr = lane & 15;
  const int fq = lane >> 4;
#pragma unroll
  for (int m = 0; m < 4; ++m) {
    const int row0 = bM + wr * 64 + m * 16 + fq * 4;
#pragma unroll
    for (int n = 0; n < 4; ++n) {
      const int col = bN + wc * 64 + n * 16 + fr;
#pragma unroll
      for (int r = 0; r < 4; ++r)
        C[(size_t)(row0 + r) * NN + col] = acc[m][n][r];
    }
  }
  if (ti != tj) {
#pragma unroll
    for (int m = 0; m < 4; ++m) {
      const int colT = bM + wr * 64 + m * 16 + fq * 4;
#pragma unroll
      for (int n = 0; n < 4; ++n) {
        const int rowT = bN + wc * 64 + n * 16 + fr;
        *(f32x4*)(C + (size_t)rowT * NN + colT) = acc[m][n];
      }
    }
  }
}

// ---------------------------------------------------------------------------
extern "C" void kernel_launch(void* const* d_in, const int* in_sizes, int n_in,
                              void* d_out, int out_size, void* d_ws, size_t ws_size,
                              hipStream_t stream)
{
  const float* x = (const float*)d_in[0];   // [B,N,C]
  const float* W = (const float*)d_in[1];   // [2*H*C, C]
  float* logits = (float*)d_out;            // f32 logits, later final out
  char* ws = (char*)d_ws;

  __bf16* qk_hi = (__bf16*)(ws + ((size_t)0   << 20));   // 64 MiB
  __bf16* qk_lo = (__bf16*)(ws + ((size_t)64  << 20));   // 64 MiB
  __bf16* attnb = (__bf16*)(ws + ((size_t)0   << 20));   // 128 MiB (reuses qk)
  __bf16* x_hi  = (__bf16*)(ws + ((size_t)128 << 20));
  __bf16* x_lo  = (__bf16*)(ws + ((size_t)132 << 20));
  __bf16* W_hi  = (__bf16*)(ws + ((size_t)136 << 20));
  __bf16* W_lo  = (__bf16*)(ws + ((size_t)138 << 20));
  float*  se    = (float*)(ws + ((size_t)144 << 20));    // 32 MiB
  float*  cmask = (float*)(ws + ((size_t)176 << 20));    // 32 KiB
  float*  irs   = (float*)(ws + ((size_t)177 << 20));    // 256 KiB
  float*  isc   = (float*)(ws + ((size_t)178 << 20));    // 256 KiB
  float*  csp   = (float*)(ws + ((size_t)180 << 20));    // 4 MiB partials
  __bf16* Gb    = (__bf16*)(ws + ((size_t)192 << 20));   // 128 MiB

  // 0. split x and W into bf16 hi/lo
  hipLaunchKernelGGL(split_kernel, dim3((BB*NN*CC/4 + 255)/256), dim3(256), 0, stream,
                     x, x_hi, x_lo, BB*NN*CC/4);
  hipLaunchKernelGGL(split_kernel, dim3((OUTCH*CC/4 + 255)/256), dim3(256), 0, stream,
                     W, W_hi, W_lo, OUTCH*CC/4);

  // 1. qk = x @ W^T (split-bf16 MFMA)
  hipLaunchKernelGGL(xw_mfma_kernel, dim3(OUTCH/128, (BB*NN)/128, 1), dim3(256), 0, stream,
                     x_hi, x_lo, W_hi, W_lo, qk_hi, qk_lo);

  // 2. logits = scale * q @ k^T -> d_out (f32), bh-resident swizzle
  hipLaunchKernelGGL(qkt_mfma_kernel, dim3(64 * 64), dim3(256), 0, stream,
                     qk_hi, qk_lo, logits);

  // 3+4. softmax (f32 logits -> bf16 attn in ws) + head-sum
  hipLaunchKernelGGL(softmax_se_kernel, dim3(BB*NN), dim3(256), 0, stream,
                     logits, attnb, se);

  // 5. top-5 union -> column mask
  hipMemsetAsync(cmask, 0, (size_t)BB * NN * 4, stream);
  hipLaunchKernelGGL(topk_kernel, dim3(BB*NN), dim3(256), 0, stream, se, cmask);

  // 6+7. fused row sums + column partials, then finalize isc
  hipLaunchKernelGGL(cs_rs_kernel, dim3(16, BB*HH), dim3(256), 0, stream,
                     attnb, cmask, irs, csp);
  hipLaunchKernelGGL(cs_fin_kernel, dim3(BB*HH), dim3(256), 0, stream, csp, isc);

  // 8. Gb = bf16( e * inv_rs * isc )
  hipLaunchKernelGGL(g_kernel, dim3((BB*HH*NN*(long long)NN) / 4 / 256), dim3(256), 0, stream,
                     attnb, cmask, irs, isc, Gb);

  // 9. out = Gb @ Gb^T (symmetric MFMA, bh-resident swizzle) -> d_out f32
  hipLaunchKernelGGL(ggt_mfma_kernel, dim3(36 * 64), dim3(256), 0, stream,
                     Gb, logits);

  (void)in_sizes; (void)n_in; (void)out_size; (void)ws_size;
}